// Round 3
// baseline (1300.132 us; speedup 1.0000x reference)
//
#include <hip/hip_runtime.h>
#include <hip/hip_bf16.h>
#include <math.h>

#define N_NODES 50000
#define E_MSG   800000
#define E_FULL  1000000
#define IN_C    128
#define H_C     64
#define T_STEPS 128

// ---- workspace layout (in floats) ----
#define OFF_Win   0
#define OFF_bin   8192
#define OFF_Wt1   8256
#define OFF_bt1   24640
#define OFF_Wt2   24896
#define OFF_bt2   41280
#define OFF_Wc0   41344
#define OFF_bc0   45440
#define OFF_Wc1   45504
#define OFF_bc1   49600
#define OFF_Wd1   49664
#define OFF_bd1   57856
#define OFF_Wd2   57920
#define OFF_bd2   57984
#define W_TOTAL   57985
#define OFF_FLAG  58000                 // 1.0f if float inputs are fp32, 0.0f if bf16
#define OFF_TEMB  65536                 // 128*64
#define OFF_DINV  73728                 // 50000
#define OFF_DEG   123904                // 50000
#define OFF_A     174080                // 3.2M floats
#define OFF_B     (174080+3200000)      // 3.2M floats
// total: 6,574,080 floats = 26.3 MB

static __device__ __forceinline__ float bf2f(unsigned short u) {
    return __uint_as_float(((unsigned)u) << 16);
}

// ---------------- input dtype detector ----------------
// W_in ~ N(0, 0.02^2). If buffer is bf16, every uint16 decodes to |v| < ~0.2.
// If buffer is fp32, even-indexed uint16s are mantissa low-halves (uniform bits)
// -> ~50% decode (as bf16) to |v| > 0.5.
__global__ void k_detect(const unsigned short* __restrict__ w, float* __restrict__ ws) {
    __shared__ int cnt;
    if (threadIdx.x == 0) cnt = 0;
    __syncthreads();
    int big = 0;
    for (int i = threadIdx.x; i < 2048; i += 256) {
        float v = bf2f(w[2 * i]);
        if (fabsf(v) > 0.5f) big++;
    }
    atomicAdd(&cnt, big);
    __syncthreads();
    if (threadIdx.x == 0) ws[OFF_FLAG] = (cnt > 64) ? 1.0f : 0.0f;
}

// ---------------- weight conversion -> fp32, packed ----------------
struct CvtArgs { const void* src[14]; };

__global__ void k_cvt(CvtArgs a, float* ws) {
    int t = blockIdx.x * 256 + threadIdx.x;
    if (t >= W_TOTAL) return;
    const int starts[14] = {OFF_Win, OFF_bin, OFF_Wt1, OFF_bt1, OFF_Wt2, OFF_bt2,
                            OFF_Wc0, OFF_bc0, OFF_Wc1, OFF_bc1, OFF_Wd1, OFF_bd1,
                            OFF_Wd2, OFF_bd2};
    int seg = 0;
#pragma unroll
    for (int i = 1; i < 14; i++)
        if (t >= starts[i]) seg = i;
    int off = t - starts[seg];
    bool f32 = (ws[OFF_FLAG] != 0.0f);
    float v = f32 ? ((const float*)a.src[seg])[off]
                  : bf2f(((const unsigned short*)a.src[seg])[off]);
    ws[t] = v;
}

// ---------------- t_emb table: only 128 distinct timesteps ----------------
__global__ void __launch_bounds__(64) k_temb(float* ws) {
    const float* Wt1 = ws + OFF_Wt1;
    const float* bt1 = ws + OFF_bt1;
    const float* Wt2 = ws + OFF_Wt2;
    const float* bt2 = ws + OFF_bt2;
    float* temb = ws + OFF_TEMB;
    int t = blockIdx.x;      // timestep 0..127
    int j = threadIdx.x;     // channel 0..63

    __shared__ float pe[64];
    __shared__ float us[256];

    float xt = (float)t * (4000.0f / 128.0f);
    float sc = -logf(10000.0f) / 31.0f;     // half-1 = 31
    int idx = j & 31;
    float fr = __expf((float)idx * sc);
    float ang = xt * fr;
    pe[j] = (j < 32) ? sinf(ang) : cosf(ang);
    __syncthreads();

    float u[4];
#pragma unroll
    for (int q = 0; q < 4; q++) u[q] = bt1[q * 64 + j];
    for (int k = 0; k < 64; k++) {
        float p = pe[k];
#pragma unroll
        for (int q = 0; q < 4; q++)
            u[q] = fmaf(p, Wt1[k * 256 + q * 64 + j], u[q]);
    }
#pragma unroll
    for (int q = 0; q < 4; q++) {
        float uu = u[q];
        us[q * 64 + j] = uu / (1.0f + __expf(-uu));   // silu
    }
    __syncthreads();

    float acc = bt2[j];
    for (int k = 0; k < 256; k++)
        acc = fmaf(us[k], Wt2[k * 64 + j], acc);
    temb[t * 64 + j] = acc;
}

// ---------------- embedder: h_embed = x @ W_in + b_in + temb[t] ----------------
__global__ void __launch_bounds__(64) k_embed(const void* __restrict__ xraw,
                                              const int* __restrict__ tsteps,
                                              float* __restrict__ ws,
                                              float* __restrict__ out_hembed) {
    int j = threadIdx.x;
    const float* Win = ws + OFF_Win;
    float wcol[128];
#pragma unroll
    for (int k = 0; k < 128; k++) wcol[k] = Win[k * 64 + j];
    float bj = ws[OFF_bin + j];
    const float* temb = ws + OFF_TEMB;
    float* A = ws + OFF_A;
    bool f32 = (ws[OFF_FLAG] != 0.0f);

    for (int i = 0; i < 8; i++) {
        int n = blockIdx.x * 8 + i;
        int tn = tsteps[n];
        float acc = bj + temb[tn * 64 + j];
        if (f32) {
            const float4* xr = reinterpret_cast<const float4*>((const float*)xraw + (size_t)n * 128);
#pragma unroll
            for (int q = 0; q < 32; q++) {
                float4 v = xr[q];
                acc = fmaf(v.x, wcol[q * 4 + 0], acc);
                acc = fmaf(v.y, wcol[q * 4 + 1], acc);
                acc = fmaf(v.z, wcol[q * 4 + 2], acc);
                acc = fmaf(v.w, wcol[q * 4 + 3], acc);
            }
        } else {
            const uint4* xr = reinterpret_cast<const uint4*>((const unsigned short*)xraw + (size_t)n * 128);
#pragma unroll
            for (int q = 0; q < 8; q++) {
                uint4 vv = xr[q];
                unsigned d0 = vv.x, d1 = vv.y, d2 = vv.z, d3 = vv.w;
                int k = q * 8;
                acc = fmaf(__uint_as_float(d0 << 16),         wcol[k + 0], acc);
                acc = fmaf(__uint_as_float(d0 & 0xffff0000u), wcol[k + 1], acc);
                acc = fmaf(__uint_as_float(d1 << 16),         wcol[k + 2], acc);
                acc = fmaf(__uint_as_float(d1 & 0xffff0000u), wcol[k + 3], acc);
                acc = fmaf(__uint_as_float(d2 << 16),         wcol[k + 4], acc);
                acc = fmaf(__uint_as_float(d2 & 0xffff0000u), wcol[k + 5], acc);
                acc = fmaf(__uint_as_float(d3 << 16),         wcol[k + 6], acc);
                acc = fmaf(__uint_as_float(d3 & 0xffff0000u), wcol[k + 7], acc);
            }
        }
        A[(size_t)n * 64 + j] = acc;
        out_hembed[(size_t)n * 64 + j] = acc;
    }
}

// ---------------- degree / dinv ----------------
__global__ void k_deg(const int* __restrict__ col, float* __restrict__ deg) {
    int t = blockIdx.x * 256 + threadIdx.x;
    if (t < E_MSG) atomicAdd(&deg[col[t]], 1.0f);
}

__global__ void k_dinv(float* ws) {
    int t = blockIdx.x * 256 + threadIdx.x;
    if (t < N_NODES) {
        float d = ws[OFF_DEG + t] + 1.0f;   // +1 self-loop
        ws[OFF_DINV + t] = rsqrtf(d);
    }
}

// ---------------- GCN linear: z = (h @ W) * dinv ; write z to BOTH zA and zB ----
// zA may alias hin (in-place): each row is read and written by exactly one
// block iteration; no cross-row dependencies, so ordering is immaterial.
__global__ void __launch_bounds__(64) k_lin(const float* __restrict__ hin,
                                            const float* __restrict__ W,
                                            const float* __restrict__ dinv,
                                            float* __restrict__ zA,
                                            float* __restrict__ zB) {
    int j = threadIdx.x;
    float wcol[64];
#pragma unroll
    for (int k = 0; k < 64; k++) wcol[k] = W[k * 64 + j];

    for (int i = 0; i < 16; i++) {
        int n = blockIdx.x * 16 + i;
        const float4* hr = reinterpret_cast<const float4*>(hin + (size_t)n * 64);
        float acc = 0.0f;
#pragma unroll
        for (int q = 0; q < 16; q++) {
            float4 h4 = hr[q];
            acc = fmaf(h4.x, wcol[q * 4 + 0], acc);
            acc = fmaf(h4.y, wcol[q * 4 + 1], acc);
            acc = fmaf(h4.z, wcol[q * 4 + 2], acc);
            acc = fmaf(h4.w, wcol[q * 4 + 3], acc);
        }
        float z = acc * dinv[n];
        zA[(size_t)n * 64 + j] = z;
        zB[(size_t)n * 64 + j] = z;   // self-loop seed for the accumulator
    }
}

// ---------------- scatter-add over edges: B[col] += A[row] ----------------
__global__ void k_scatter(const int* __restrict__ row, const int* __restrict__ col,
                          const float* __restrict__ z, float* __restrict__ acc) {
    int t = blockIdx.x * 256 + threadIdx.x;
    int e = t >> 6;
    int ch = t & 63;
    if (e < E_MSG) {
        int r = row[e], c = col[e];
        atomicAdd(&acc[(size_t)c * 64 + ch], z[(size_t)r * 64 + ch]);
    }
}

// ---------------- finalize: h = act(dinv*accB + b) ----------------
template <bool RELU, bool WRITE_OUT>
__global__ void k_fin(const float* __restrict__ accb,
                      const float* __restrict__ dinv, const float* __restrict__ bias,
                      float* __restrict__ hout, float* __restrict__ ofp) {
    int t = blockIdx.x * 256 + threadIdx.x;
    if (t >= N_NODES * 64) return;
    int n = t >> 6;
    int j = t & 63;
    float v = dinv[n] * accb[t] + bias[j];
    if (RELU) v = fmaxf(v, 0.0f);
    hout[t] = v;
    if (WRITE_OUT) ofp[t] = v;
}

// ---------------- edge decoder ----------------
__global__ void __launch_bounds__(64) k_dec(const int* __restrict__ src,
                                            const int* __restrict__ dst,
                                            const float* __restrict__ henc,
                                            const float* __restrict__ ws,
                                            float* __restrict__ out) {
    int j = threadIdx.x;  // hidden channel
    const float* Wd1 = ws + OFF_Wd1;
    float wcol[128];
#pragma unroll
    for (int k = 0; k < 128; k++) wcol[k] = Wd1[k * 64 + j];
    float w2 = ws[OFF_Wd2 + j];
    float b1 = ws[OFF_bd1 + j];
    float b2 = ws[OFF_bd2];

    for (int i = 0; i < 16; i++) {
        int e = blockIdx.x * 16 + i;
        int s = src[e];
        int d = dst[e];
        const float4* fs = reinterpret_cast<const float4*>(henc + (size_t)s * 64);
        const float4* fd = reinterpret_cast<const float4*>(henc + (size_t)d * 64);
        float acc = b1;
#pragma unroll
        for (int q = 0; q < 16; q++) {
            float4 v = fs[q];
            acc = fmaf(v.x, wcol[q * 4 + 0], acc);
            acc = fmaf(v.y, wcol[q * 4 + 1], acc);
            acc = fmaf(v.z, wcol[q * 4 + 2], acc);
            acc = fmaf(v.w, wcol[q * 4 + 3], acc);
        }
#pragma unroll
        for (int q = 0; q < 16; q++) {
            float4 v = fd[q];
            acc = fmaf(v.x, wcol[64 + q * 4 + 0], acc);
            acc = fmaf(v.y, wcol[64 + q * 4 + 1], acc);
            acc = fmaf(v.z, wcol[64 + q * 4 + 2], acc);
            acc = fmaf(v.w, wcol[64 + q * 4 + 3], acc);
        }
        float hid = acc / (1.0f + __expf(-acc));   // silu
        float contrib = hid * w2;
#pragma unroll
        for (int m = 32; m >= 1; m >>= 1)
            contrib += __shfl_xor(contrib, m, 64);
        if (j == 0) out[e] = contrib + b2;
    }
}

extern "C" void kernel_launch(void* const* d_in, const int* in_sizes, int n_in,
                              void* d_out, int out_size, void* d_ws, size_t ws_size,
                              hipStream_t stream) {
    if (n_in < 18) return;
    const void* x              = d_in[0];
    const int* edge_index      = (const int*)d_in[1];
    const int* full_edge_index = (const int*)d_in[2];
    const int* tsteps          = (const int*)d_in[3];
    float* ws = (float*)d_ws;
    float* out = (float*)d_out;

    CvtArgs ca;
    for (int i = 0; i < 14; i++) ca.src[i] = d_in[4 + i];

    // dtype flag, weights -> fp32, t_emb table
    k_detect<<<1, 256, 0, stream>>>((const unsigned short*)d_in[4], ws);
    k_cvt<<<(W_TOTAL + 255) / 256, 256, 0, stream>>>(ca, ws);
    k_temb<<<T_STEPS, 64, 0, stream>>>(ws);

    // embedder (writes h_embed: fp32 -> A, fp32 -> out)
    k_embed<<<N_NODES / 8, 64, 0, stream>>>(x, tsteps, ws, out + E_FULL);

    // degree / dinv
    hipMemsetAsync(ws + OFF_DEG, 0, (size_t)N_NODES * 4, stream);
    k_deg<<<(E_MSG + 255) / 256, 256, 0, stream>>>(edge_index + E_MSG, ws + OFF_DEG);
    k_dinv<<<(N_NODES + 255) / 256, 256, 0, stream>>>(ws);

    // GCN layer 0: A(h_embed) -> z in A and B -> scatter A into B -> fin B -> A(h1)
    k_lin<<<N_NODES / 16, 64, 0, stream>>>(ws + OFF_A, ws + OFF_Wc0, ws + OFF_DINV,
                                           ws + OFF_A, ws + OFF_B);
    k_scatter<<<(E_MSG * 64) / 256, 256, 0, stream>>>(edge_index, edge_index + E_MSG,
                                                      ws + OFF_A, ws + OFF_B);
    k_fin<true, false><<<(N_NODES * 64) / 256, 256, 0, stream>>>(
        ws + OFF_B, ws + OFF_DINV, ws + OFF_bc0, ws + OFF_A, nullptr);

    // GCN layer 1
    k_lin<<<N_NODES / 16, 64, 0, stream>>>(ws + OFF_A, ws + OFF_Wc1, ws + OFF_DINV,
                                           ws + OFF_A, ws + OFF_B);
    k_scatter<<<(E_MSG * 64) / 256, 256, 0, stream>>>(edge_index, edge_index + E_MSG,
                                                      ws + OFF_A, ws + OFF_B);
    k_fin<false, true><<<(N_NODES * 64) / 256, 256, 0, stream>>>(
        ws + OFF_B, ws + OFF_DINV, ws + OFF_bc1, ws + OFF_A,
        out + E_FULL + (size_t)N_NODES * 64);

    // decoder
    k_dec<<<E_FULL / 16, 64, 0, stream>>>(full_edge_index, full_edge_index + E_FULL,
                                          ws + OFF_A, ws, out);
}

// Round 4
// 729.744 us; speedup vs baseline: 1.7816x; 1.7816x over previous
//
#include <hip/hip_runtime.h>
#include <hip/hip_bf16.h>
#include <math.h>

#define N_NODES 50000
#define E_MSG   800000
#define E_FULL  1000000
#define IN_C    128
#define H_C     64
#define T_STEPS 128

// ---- workspace layout (in floats) ----
#define OFF_Win   0
#define OFF_bin   8192
#define OFF_Wt1   8256
#define OFF_bt1   24640
#define OFF_Wt2   24896
#define OFF_bt2   41280
#define OFF_Wc0   41344
#define OFF_bc0   45440
#define OFF_Wc1   45504
#define OFF_bc1   49600
#define OFF_Wd1   49664
#define OFF_bd1   57856
#define OFF_Wd2   57920
#define OFF_bd2   57984
#define W_TOTAL   57985
#define OFF_FLAG  58000                 // 1.0f if float inputs are fp32, 0.0f if bf16
#define OFF_TEMB  65536                 // 128*64
#define OFF_DINV  73728                 // 50000
#define OFF_DEG   123904                // 50000
#define OFF_A     174080                // 3.2M floats (h_embed/h1 fp32; then h_enc bf16)
#define OFF_B     (174080+3200000)      // 3.2M floats
// total: 6,574,080 floats = 26.3 MB

typedef __attribute__((ext_vector_type(8))) short bf16x8;
typedef __attribute__((ext_vector_type(4))) float f32x4;

static __device__ __forceinline__ float bf2f(unsigned short u) {
    return __uint_as_float(((unsigned)u) << 16);
}
static __device__ __forceinline__ unsigned short f2bf(float f) {
    unsigned u = __float_as_uint(f);
    unsigned r = (u + 0x7fffu + ((u >> 16) & 1u)) >> 16;
    return (unsigned short)r;
}

// ---------------- input dtype detector ----------------
__global__ void k_detect(const unsigned short* __restrict__ w, float* __restrict__ ws) {
    __shared__ int cnt;
    if (threadIdx.x == 0) cnt = 0;
    __syncthreads();
    int big = 0;
    for (int i = threadIdx.x; i < 2048; i += 256) {
        float v = bf2f(w[2 * i]);
        if (fabsf(v) > 0.5f) big++;
    }
    atomicAdd(&cnt, big);
    __syncthreads();
    if (threadIdx.x == 0) ws[OFF_FLAG] = (cnt > 64) ? 1.0f : 0.0f;
}

// ---------------- weight conversion -> fp32, packed ----------------
struct CvtArgs { const void* src[14]; };

__global__ void k_cvt(CvtArgs a, float* ws) {
    int t = blockIdx.x * 256 + threadIdx.x;
    if (t >= W_TOTAL) return;
    const int starts[14] = {OFF_Win, OFF_bin, OFF_Wt1, OFF_bt1, OFF_Wt2, OFF_bt2,
                            OFF_Wc0, OFF_bc0, OFF_Wc1, OFF_bc1, OFF_Wd1, OFF_bd1,
                            OFF_Wd2, OFF_bd2};
    int seg = 0;
#pragma unroll
    for (int i = 1; i < 14; i++)
        if (t >= starts[i]) seg = i;
    int off = t - starts[seg];
    bool f32 = (ws[OFF_FLAG] != 0.0f);
    float v = f32 ? ((const float*)a.src[seg])[off]
                  : bf2f(((const unsigned short*)a.src[seg])[off]);
    ws[t] = v;
}

// ---------------- t_emb table: only 128 distinct timesteps ----------------
__global__ void __launch_bounds__(64) k_temb(float* ws) {
    const float* Wt1 = ws + OFF_Wt1;
    const float* bt1 = ws + OFF_bt1;
    const float* Wt2 = ws + OFF_Wt2;
    const float* bt2 = ws + OFF_bt2;
    float* temb = ws + OFF_TEMB;
    int t = blockIdx.x;      // timestep 0..127
    int j = threadIdx.x;     // channel 0..63

    __shared__ float pe[64];
    __shared__ float us[256];

    float xt = (float)t * (4000.0f / 128.0f);
    float sc = -logf(10000.0f) / 31.0f;     // half-1 = 31
    int idx = j & 31;
    float fr = __expf((float)idx * sc);
    float ang = xt * fr;
    pe[j] = (j < 32) ? sinf(ang) : cosf(ang);
    __syncthreads();

    float u[4];
#pragma unroll
    for (int q = 0; q < 4; q++) u[q] = bt1[q * 64 + j];
    for (int k = 0; k < 64; k++) {
        float p = pe[k];
#pragma unroll
        for (int q = 0; q < 4; q++)
            u[q] = fmaf(p, Wt1[k * 256 + q * 64 + j], u[q]);
    }
#pragma unroll
    for (int q = 0; q < 4; q++) {
        float uu = u[q];
        us[q * 64 + j] = uu / (1.0f + __expf(-uu));   // silu
    }
    __syncthreads();

    float acc = bt2[j];
    for (int k = 0; k < 256; k++)
        acc = fmaf(us[k], Wt2[k * 64 + j], acc);
    temb[t * 64 + j] = acc;
}

// ---------------- embedder: h_embed = x @ W_in + b_in + temb[t] ----------------
__global__ void __launch_bounds__(64) k_embed(const void* __restrict__ xraw,
                                              const int* __restrict__ tsteps,
                                              float* __restrict__ ws,
                                              float* __restrict__ out_hembed) {
    int j = threadIdx.x;
    const float* Win = ws + OFF_Win;
    float wcol[128];
#pragma unroll
    for (int k = 0; k < 128; k++) wcol[k] = Win[k * 64 + j];
    float bj = ws[OFF_bin + j];
    const float* temb = ws + OFF_TEMB;
    float* A = ws + OFF_A;
    bool f32 = (ws[OFF_FLAG] != 0.0f);

    for (int i = 0; i < 8; i++) {
        int n = blockIdx.x * 8 + i;
        int tn = tsteps[n];
        float acc = bj + temb[tn * 64 + j];
        if (f32) {
            const float4* xr = reinterpret_cast<const float4*>((const float*)xraw + (size_t)n * 128);
#pragma unroll
            for (int q = 0; q < 32; q++) {
                float4 v = xr[q];
                acc = fmaf(v.x, wcol[q * 4 + 0], acc);
                acc = fmaf(v.y, wcol[q * 4 + 1], acc);
                acc = fmaf(v.z, wcol[q * 4 + 2], acc);
                acc = fmaf(v.w, wcol[q * 4 + 3], acc);
            }
        } else {
            const uint4* xr = reinterpret_cast<const uint4*>((const unsigned short*)xraw + (size_t)n * 128);
#pragma unroll
            for (int q = 0; q < 8; q++) {
                uint4 vv = xr[q];
                unsigned d0 = vv.x, d1 = vv.y, d2 = vv.z, d3 = vv.w;
                int k = q * 8;
                acc = fmaf(__uint_as_float(d0 << 16),         wcol[k + 0], acc);
                acc = fmaf(__uint_as_float(d0 & 0xffff0000u), wcol[k + 1], acc);
                acc = fmaf(__uint_as_float(d1 << 16),         wcol[k + 2], acc);
                acc = fmaf(__uint_as_float(d1 & 0xffff0000u), wcol[k + 3], acc);
                acc = fmaf(__uint_as_float(d2 << 16),         wcol[k + 4], acc);
                acc = fmaf(__uint_as_float(d2 & 0xffff0000u), wcol[k + 5], acc);
                acc = fmaf(__uint_as_float(d3 << 16),         wcol[k + 6], acc);
                acc = fmaf(__uint_as_float(d3 & 0xffff0000u), wcol[k + 7], acc);
            }
        }
        A[(size_t)n * 64 + j] = acc;
        out_hembed[(size_t)n * 64 + j] = acc;
    }
}

// ---------------- degree / dinv ----------------
__global__ void k_deg(const int* __restrict__ col, float* __restrict__ deg) {
    int t = blockIdx.x * 256 + threadIdx.x;
    if (t < E_MSG) atomicAdd(&deg[col[t]], 1.0f);
}

__global__ void k_dinv(float* ws) {
    int t = blockIdx.x * 256 + threadIdx.x;
    if (t < N_NODES) {
        float d = ws[OFF_DEG + t] + 1.0f;   // +1 self-loop
        ws[OFF_DINV + t] = rsqrtf(d);
    }
}

// ---------------- GCN linear: z = (h @ W) * dinv ; write z to BOTH zA and zB ----
__global__ void __launch_bounds__(64) k_lin(const float* __restrict__ hin,
                                            const float* __restrict__ W,
                                            const float* __restrict__ dinv,
                                            float* __restrict__ zA,
                                            float* __restrict__ zB) {
    int j = threadIdx.x;
    float wcol[64];
#pragma unroll
    for (int k = 0; k < 64; k++) wcol[k] = W[k * 64 + j];

    for (int i = 0; i < 16; i++) {
        int n = blockIdx.x * 16 + i;
        const float4* hr = reinterpret_cast<const float4*>(hin + (size_t)n * 64);
        float acc = 0.0f;
#pragma unroll
        for (int q = 0; q < 16; q++) {
            float4 h4 = hr[q];
            acc = fmaf(h4.x, wcol[q * 4 + 0], acc);
            acc = fmaf(h4.y, wcol[q * 4 + 1], acc);
            acc = fmaf(h4.z, wcol[q * 4 + 2], acc);
            acc = fmaf(h4.w, wcol[q * 4 + 3], acc);
        }
        float z = acc * dinv[n];
        zA[(size_t)n * 64 + j] = z;
        zB[(size_t)n * 64 + j] = z;   // self-loop seed for the accumulator
    }
}

// ---------------- scatter-add over edges: B[col] += A[row] ----------------
__global__ void k_scatter(const int* __restrict__ row, const int* __restrict__ col,
                          const float* __restrict__ z, float* __restrict__ acc) {
    int t = blockIdx.x * 256 + threadIdx.x;
    int e = t >> 6;
    int ch = t & 63;
    if (e < E_MSG) {
        int r = row[e], c = col[e];
        atomicAdd(&acc[(size_t)c * 64 + ch], z[(size_t)r * 64 + ch]);
    }
}

// ---------------- finalize layer0: h1 = relu(dinv*accB + b) -> fp32 ----------------
__global__ void k_fin0(const float* __restrict__ accb,
                       const float* __restrict__ dinv, const float* __restrict__ bias,
                       float* __restrict__ hout) {
    int t = blockIdx.x * 256 + threadIdx.x;
    if (t >= N_NODES * 64) return;
    int n = t >> 6;
    int j = t & 63;
    float v = dinv[n] * accb[t] + bias[j];
    v = fmaxf(v, 0.0f);
    hout[t] = v;
}

// ---------------- finalize layer1: h_enc -> fp32 d_out + bf16 table ----------------
__global__ void k_fin1(const float* __restrict__ accb,
                       const float* __restrict__ dinv, const float* __restrict__ bias,
                       unsigned short* __restrict__ hbf, float* __restrict__ ofp) {
    int t = blockIdx.x * 256 + threadIdx.x;
    if (t >= N_NODES * 64) return;
    int n = t >> 6;
    int j = t & 63;
    float v = dinv[n] * accb[t] + bias[j];
    ofp[t] = v;
    hbf[t] = f2bf(v);
}

// ---------------- edge decoder (MFMA bf16) ----------------
// Per 16-edge tile: A = feat[16 x 128] bf16 (dims 0..63 = src row, 64..127 = dst),
// B = Wd1[128 x 64] bf16 in registers; C[16 x 64] via 4 K-chunks x 4 N-tiles of
// mfma_f32_16x16x32_bf16. A layout: A[m=lane&15][k=quad*8+j]; C: col=lane&15,
// row=quad*4+reg. Epilogue: silu(+b1) dot w2 via 4-step shuffle reduce.
#define DEC_TPW 8
#define DEC_TILES (E_FULL / 16)

__global__ void __launch_bounds__(256) k_dec(const int* __restrict__ src,
                                             const int* __restrict__ dst,
                                             const unsigned short* __restrict__ hbf,
                                             const float* __restrict__ ws,
                                             float* __restrict__ out) {
    int lane = threadIdx.x & 63;
    int wv = threadIdx.x >> 6;
    int m = lane & 15;
    int quad = lane >> 4;

    // B fragments: bfr[chunk][ntile], element j -> Wd1[32c + 8*quad + j][16t + m]
    bf16x8 bfr[4][4];
#pragma unroll
    for (int c = 0; c < 4; c++)
#pragma unroll
        for (int t = 0; t < 4; t++) {
            bf16x8 b;
#pragma unroll
            for (int j = 0; j < 8; j++)
                b[j] = (short)f2bf(ws[OFF_Wd1 + (32 * c + 8 * quad + j) * 64 + 16 * t + m]);
            bfr[c][t] = b;
        }
    float w2[4], b1v[4];
#pragma unroll
    for (int t = 0; t < 4; t++) {
        w2[t]  = ws[OFF_Wd2 + 16 * t + m];
        b1v[t] = ws[OFF_bd1 + 16 * t + m];
    }
    float b2 = ws[OFF_bd2];

    int tile0 = (blockIdx.x * 4 + wv) * DEC_TPW;
    for (int i = 0; i < DEC_TPW; i++) {
        int tile = tile0 + i;
        if (tile >= DEC_TILES) break;
        int e0 = tile * 16;
        int s = src[e0 + m];
        int d = dst[e0 + m];
        f32x4 acc[4] = {f32x4{0,0,0,0}, f32x4{0,0,0,0}, f32x4{0,0,0,0}, f32x4{0,0,0,0}};
#pragma unroll
        for (int c = 0; c < 4; c++) {
            int row = (c < 2) ? s : d;
            const bf16x8* ap = reinterpret_cast<const bf16x8*>(
                hbf + (size_t)row * 64 + (c & 1) * 32 + 8 * quad);
            bf16x8 a = *ap;
#pragma unroll
            for (int t = 0; t < 4; t++)
                acc[t] = __builtin_amdgcn_mfma_f32_16x16x32_bf16(a, bfr[c][t], acc[t], 0, 0, 0);
        }
        float sums[4];
#pragma unroll
        for (int r = 0; r < 4; r++) {
            float sv = 0.0f;
#pragma unroll
            for (int t = 0; t < 4; t++) {
                float v = acc[t][r] + b1v[t];
                float h = v / (1.0f + __expf(-v));
                sv = fmaf(h, w2[t], sv);
            }
#pragma unroll
            for (int msk = 8; msk >= 1; msk >>= 1)
                sv += __shfl_xor(sv, msk, 64);
            sums[r] = sv;
        }
        if (m == 0) {
            int ebase = e0 + 4 * quad;
#pragma unroll
            for (int r = 0; r < 4; r++) out[ebase + r] = sums[r] + b2;
        }
    }
}

extern "C" void kernel_launch(void* const* d_in, const int* in_sizes, int n_in,
                              void* d_out, int out_size, void* d_ws, size_t ws_size,
                              hipStream_t stream) {
    if (n_in < 18) return;
    const void* x              = d_in[0];
    const int* edge_index      = (const int*)d_in[1];
    const int* full_edge_index = (const int*)d_in[2];
    const int* tsteps          = (const int*)d_in[3];
    float* ws = (float*)d_ws;
    float* out = (float*)d_out;

    CvtArgs ca;
    for (int i = 0; i < 14; i++) ca.src[i] = d_in[4 + i];

    // dtype flag, weights -> fp32, t_emb table
    k_detect<<<1, 256, 0, stream>>>((const unsigned short*)d_in[4], ws);
    k_cvt<<<(W_TOTAL + 255) / 256, 256, 0, stream>>>(ca, ws);
    k_temb<<<T_STEPS, 64, 0, stream>>>(ws);

    // embedder (writes h_embed: fp32 -> A, fp32 -> out)
    k_embed<<<N_NODES / 8, 64, 0, stream>>>(x, tsteps, ws, out + E_FULL);

    // degree / dinv
    hipMemsetAsync(ws + OFF_DEG, 0, (size_t)N_NODES * 4, stream);
    k_deg<<<(E_MSG + 255) / 256, 256, 0, stream>>>(edge_index + E_MSG, ws + OFF_DEG);
    k_dinv<<<(N_NODES + 255) / 256, 256, 0, stream>>>(ws);

    // GCN layer 0: A(h_embed) -> z in A and B -> scatter A into B -> fin B -> A(h1)
    k_lin<<<N_NODES / 16, 64, 0, stream>>>(ws + OFF_A, ws + OFF_Wc0, ws + OFF_DINV,
                                           ws + OFF_A, ws + OFF_B);
    k_scatter<<<(E_MSG * 64) / 256, 256, 0, stream>>>(edge_index, edge_index + E_MSG,
                                                      ws + OFF_A, ws + OFF_B);
    k_fin0<<<(N_NODES * 64) / 256, 256, 0, stream>>>(
        ws + OFF_B, ws + OFF_DINV, ws + OFF_bc0, ws + OFF_A);

    // GCN layer 1: A(h1) -> z in A and B -> scatter A into B -> fin B -> {out fp32, A bf16}
    k_lin<<<N_NODES / 16, 64, 0, stream>>>(ws + OFF_A, ws + OFF_Wc1, ws + OFF_DINV,
                                           ws + OFF_A, ws + OFF_B);
    k_scatter<<<(E_MSG * 64) / 256, 256, 0, stream>>>(edge_index, edge_index + E_MSG,
                                                      ws + OFF_A, ws + OFF_B);
    k_fin1<<<(N_NODES * 64) / 256, 256, 0, stream>>>(
        ws + OFF_B, ws + OFF_DINV, ws + OFF_bc1,
        (unsigned short*)(ws + OFF_A), out + E_FULL + (size_t)N_NODES * 64);

    // decoder (MFMA): 62500 tiles / (4 waves * 8 tiles) per block
    int dec_blocks = (DEC_TILES + 4 * DEC_TPW - 1) / (4 * DEC_TPW);
    k_dec<<<dec_blocks, 256, 0, stream>>>(full_edge_index, full_edge_index + E_FULL,
                                          (const unsigned short*)(ws + OFF_A), ws, out);
}

// Round 5
// 597.618 us; speedup vs baseline: 2.1755x; 1.2211x over previous
//
#include <hip/hip_runtime.h>
#include <hip/hip_bf16.h>
#include <math.h>

#define N_NODES 50000
#define E_MSG   800000
#define E_FULL  1000000
#define IN_C    128
#define H_C     64
#define T_STEPS 128

// ---- workspace layout (in floats) ----
#define OFF_Win   0
#define OFF_bin   8192
#define OFF_Wt1   8256
#define OFF_bt1   24640
#define OFF_Wt2   24896
#define OFF_bt2   41280
#define OFF_Wc0   41344
#define OFF_bc0   45440
#define OFF_Wc1   45504
#define OFF_bc1   49600
#define OFF_Wd1   49664
#define OFF_bd1   57856
#define OFF_Wd2   57920
#define OFF_bd2   57984
#define W_TOTAL   57985
#define OFF_FLAG  58000                 // 1.0f if float inputs are fp32, 0.0f if bf16
#define OFF_TEMB  65536                 // 128*64
#define OFF_DINV  73728                 // 50000 floats
#define OFF_CNT   123904                // 50000 ints (in-degree histogram)
#define OFF_PTR   173904                // 50001 ints (CSR row pointers, by dst)
#define OFF_CUR   223936                // 50000 ints (fill cursors)
#define OFF_ELIST 274432                // 800000 ints (src node per CSR slot)
#define OFF_A     1074432               // 3.2M floats (h_embed -> h1, fp32)
#define OFF_ZBF   4274432               // 1.6M floats = 3.2M bf16 (z table)
#define OFF_HENC  5874432               // 1.6M floats = 3.2M bf16 (h_enc for decoder)
// total: 7,474,432 floats = 29.9 MB

typedef __attribute__((ext_vector_type(8))) short bf16x8;
typedef __attribute__((ext_vector_type(4))) float f32x4;

static __device__ __forceinline__ float bf2f(unsigned short u) {
    return __uint_as_float(((unsigned)u) << 16);
}
static __device__ __forceinline__ unsigned short f2bf(float f) {
    unsigned u = __float_as_uint(f);
    unsigned r = (u + 0x7fffu + ((u >> 16) & 1u)) >> 16;
    return (unsigned short)r;
}

// ---------------- input dtype detector ----------------
__global__ void k_detect(const unsigned short* __restrict__ w, float* __restrict__ ws) {
    __shared__ int cnt;
    if (threadIdx.x == 0) cnt = 0;
    __syncthreads();
    int big = 0;
    for (int i = threadIdx.x; i < 2048; i += 256) {
        float v = bf2f(w[2 * i]);
        if (fabsf(v) > 0.5f) big++;
    }
    atomicAdd(&cnt, big);
    __syncthreads();
    if (threadIdx.x == 0) ws[OFF_FLAG] = (cnt > 64) ? 1.0f : 0.0f;
}

// ---------------- weight conversion -> fp32, packed ----------------
struct CvtArgs { const void* src[14]; };

__global__ void k_cvt(CvtArgs a, float* ws) {
    int t = blockIdx.x * 256 + threadIdx.x;
    if (t >= W_TOTAL) return;
    const int starts[14] = {OFF_Win, OFF_bin, OFF_Wt1, OFF_bt1, OFF_Wt2, OFF_bt2,
                            OFF_Wc0, OFF_bc0, OFF_Wc1, OFF_bc1, OFF_Wd1, OFF_bd1,
                            OFF_Wd2, OFF_bd2};
    int seg = 0;
#pragma unroll
    for (int i = 1; i < 14; i++)
        if (t >= starts[i]) seg = i;
    int off = t - starts[seg];
    bool f32 = (ws[OFF_FLAG] != 0.0f);
    float v = f32 ? ((const float*)a.src[seg])[off]
                  : bf2f(((const unsigned short*)a.src[seg])[off]);
    ws[t] = v;
}

// ---------------- t_emb table: only 128 distinct timesteps ----------------
__global__ void __launch_bounds__(64) k_temb(float* ws) {
    const float* Wt1 = ws + OFF_Wt1;
    const float* bt1 = ws + OFF_bt1;
    const float* Wt2 = ws + OFF_Wt2;
    const float* bt2 = ws + OFF_bt2;
    float* temb = ws + OFF_TEMB;
    int t = blockIdx.x;      // timestep 0..127
    int j = threadIdx.x;     // channel 0..63

    __shared__ float pe[64];
    __shared__ float us[256];

    float xt = (float)t * (4000.0f / 128.0f);
    float sc = -logf(10000.0f) / 31.0f;     // half-1 = 31
    int idx = j & 31;
    float fr = __expf((float)idx * sc);
    float ang = xt * fr;
    pe[j] = (j < 32) ? sinf(ang) : cosf(ang);
    __syncthreads();

    float u[4];
#pragma unroll
    for (int q = 0; q < 4; q++) u[q] = bt1[q * 64 + j];
    for (int k = 0; k < 64; k++) {
        float p = pe[k];
#pragma unroll
        for (int q = 0; q < 4; q++)
            u[q] = fmaf(p, Wt1[k * 256 + q * 64 + j], u[q]);
    }
#pragma unroll
    for (int q = 0; q < 4; q++) {
        float uu = u[q];
        us[q * 64 + j] = uu / (1.0f + __expf(-uu));   // silu
    }
    __syncthreads();

    float acc = bt2[j];
    for (int k = 0; k < 256; k++)
        acc = fmaf(us[k], Wt2[k * 64 + j], acc);
    temb[t * 64 + j] = acc;
}

// ---------------- embedder: h_embed = x @ W_in + b_in + temb[t] ----------------
__global__ void __launch_bounds__(64) k_embed(const void* __restrict__ xraw,
                                              const int* __restrict__ tsteps,
                                              float* __restrict__ ws,
                                              float* __restrict__ out_hembed) {
    int j = threadIdx.x;
    const float* Win = ws + OFF_Win;
    float wcol[128];
#pragma unroll
    for (int k = 0; k < 128; k++) wcol[k] = Win[k * 64 + j];
    float bj = ws[OFF_bin + j];
    const float* temb = ws + OFF_TEMB;
    float* A = ws + OFF_A;
    bool f32 = (ws[OFF_FLAG] != 0.0f);

    for (int i = 0; i < 8; i++) {
        int n = blockIdx.x * 8 + i;
        int tn = tsteps[n];
        float acc = bj + temb[tn * 64 + j];
        if (f32) {
            const float4* xr = reinterpret_cast<const float4*>((const float*)xraw + (size_t)n * 128);
#pragma unroll
            for (int q = 0; q < 32; q++) {
                float4 v = xr[q];
                acc = fmaf(v.x, wcol[q * 4 + 0], acc);
                acc = fmaf(v.y, wcol[q * 4 + 1], acc);
                acc = fmaf(v.z, wcol[q * 4 + 2], acc);
                acc = fmaf(v.w, wcol[q * 4 + 3], acc);
            }
        } else {
            const uint4* xr = reinterpret_cast<const uint4*>((const unsigned short*)xraw + (size_t)n * 128);
#pragma unroll
            for (int q = 0; q < 8; q++) {
                uint4 vv = xr[q];
                unsigned d0 = vv.x, d1 = vv.y, d2 = vv.z, d3 = vv.w;
                int k = q * 8;
                acc = fmaf(__uint_as_float(d0 << 16),         wcol[k + 0], acc);
                acc = fmaf(__uint_as_float(d0 & 0xffff0000u), wcol[k + 1], acc);
                acc = fmaf(__uint_as_float(d1 << 16),         wcol[k + 2], acc);
                acc = fmaf(__uint_as_float(d1 & 0xffff0000u), wcol[k + 3], acc);
                acc = fmaf(__uint_as_float(d2 << 16),         wcol[k + 4], acc);
                acc = fmaf(__uint_as_float(d2 & 0xffff0000u), wcol[k + 5], acc);
                acc = fmaf(__uint_as_float(d3 << 16),         wcol[k + 6], acc);
                acc = fmaf(__uint_as_float(d3 & 0xffff0000u), wcol[k + 7], acc);
            }
        }
        A[(size_t)n * 64 + j] = acc;
        out_hembed[(size_t)n * 64 + j] = acc;
    }
}

// ---------------- CSR build: count -> scan -> fill ----------------
__global__ void k_count(const int* __restrict__ col, int* __restrict__ cnt) {
    int t = blockIdx.x * 256 + threadIdx.x;
    if (t < E_MSG) atomicAdd(&cnt[col[t]], 1);
}

// single block: exclusive scan of cnt -> ptr/cur; dinv = rsqrt(cnt+1)
__global__ void __launch_bounds__(1024) k_scan(const int* __restrict__ cnt,
                                               int* __restrict__ ptr,
                                               int* __restrict__ cur,
                                               float* __restrict__ dinv) {
    __shared__ int psum[1024];
    int t = threadIdx.x;
    int lo = t * 49;
    int hi = lo + 49; if (hi > N_NODES) hi = N_NODES;
    int s = 0;
    for (int i = lo; i < hi; i++) s += cnt[i];
    psum[t] = s;
    __syncthreads();
    for (int off = 1; off < 1024; off <<= 1) {
        int v = (t >= off) ? psum[t - off] : 0;
        __syncthreads();
        psum[t] += v;
        __syncthreads();
    }
    int run = (t > 0) ? psum[t - 1] : 0;
    for (int i = lo; i < hi; i++) {
        ptr[i] = run;
        cur[i] = run;
        dinv[i] = rsqrtf((float)cnt[i] + 1.0f);
        run += cnt[i];
    }
    if (t == 1023) ptr[N_NODES] = run;
}

__global__ void k_fill(const int* __restrict__ row, const int* __restrict__ col,
                       int* __restrict__ cur, int* __restrict__ elist) {
    int t = blockIdx.x * 256 + threadIdx.x;
    if (t < E_MSG) {
        int c = col[t];
        int pos = atomicAdd(&cur[c], 1);
        elist[pos] = row[t];
    }
}

// ---------------- GCN linear: zbf = bf16((h @ W) * dinv) ----------------
__global__ void __launch_bounds__(64) k_lin(const float* __restrict__ hin,
                                            const float* __restrict__ W,
                                            const float* __restrict__ dinv,
                                            unsigned short* __restrict__ zbf) {
    int j = threadIdx.x;
    float wcol[64];
#pragma unroll
    for (int k = 0; k < 64; k++) wcol[k] = W[k * 64 + j];

    for (int i = 0; i < 16; i++) {
        int n = blockIdx.x * 16 + i;
        const float4* hr = reinterpret_cast<const float4*>(hin + (size_t)n * 64);
        float acc = 0.0f;
#pragma unroll
        for (int q = 0; q < 16; q++) {
            float4 h4 = hr[q];
            acc = fmaf(h4.x, wcol[q * 4 + 0], acc);
            acc = fmaf(h4.y, wcol[q * 4 + 1], acc);
            acc = fmaf(h4.z, wcol[q * 4 + 2], acc);
            acc = fmaf(h4.w, wcol[q * 4 + 3], acc);
        }
        zbf[(size_t)n * 64 + j] = f2bf(acc * dinv[n]);
    }
}

// ---------------- fused gather + finalize ----------------
// one wave per dst node, lane = channel. sum = z[self] + sum_{e in CSR[n]} z[src_e]
// h = act(dinv[n]*sum + bias)
template <bool RELU, bool WRITE_OUT>
__global__ void __launch_bounds__(256) k_gather(const unsigned short* __restrict__ zbf,
                                                const int* __restrict__ ptr,
                                                const int* __restrict__ elist,
                                                const float* __restrict__ dinv,
                                                const float* __restrict__ bias,
                                                float* __restrict__ hout,
                                                unsigned short* __restrict__ hencbf,
                                                float* __restrict__ ofp) {
    int n = blockIdx.x * 4 + (threadIdx.x >> 6);
    int j = threadIdx.x & 63;
    int base = ptr[n];
    int end  = ptr[n + 1];
    float sum = bf2f(zbf[(size_t)n * 64 + j]);   // self-loop
    int k = base;
    for (; k + 4 <= end; k += 4) {
        int r0 = elist[k], r1 = elist[k + 1], r2 = elist[k + 2], r3 = elist[k + 3];
        float v0 = bf2f(zbf[(size_t)r0 * 64 + j]);
        float v1 = bf2f(zbf[(size_t)r1 * 64 + j]);
        float v2 = bf2f(zbf[(size_t)r2 * 64 + j]);
        float v3 = bf2f(zbf[(size_t)r3 * 64 + j]);
        sum += (v0 + v1) + (v2 + v3);
    }
    for (; k < end; k++)
        sum += bf2f(zbf[(size_t)elist[k] * 64 + j]);
    float v = dinv[n] * sum + bias[j];
    if (RELU) v = fmaxf(v, 0.0f);
    size_t t = (size_t)n * 64 + j;
    if (WRITE_OUT) {
        ofp[t] = v;
        hencbf[t] = f2bf(v);
    } else {
        hout[t] = v;
    }
}

// ---------------- edge decoder (MFMA bf16) ----------------
#define DEC_TPW 8
#define DEC_TILES (E_FULL / 16)

__global__ void __launch_bounds__(256) k_dec(const int* __restrict__ src,
                                             const int* __restrict__ dst,
                                             const unsigned short* __restrict__ hbf,
                                             const float* __restrict__ ws,
                                             float* __restrict__ out) {
    int lane = threadIdx.x & 63;
    int wv = threadIdx.x >> 6;
    int m = lane & 15;
    int quad = lane >> 4;

    bf16x8 bfr[4][4];
#pragma unroll
    for (int c = 0; c < 4; c++)
#pragma unroll
        for (int t = 0; t < 4; t++) {
            bf16x8 b;
#pragma unroll
            for (int j = 0; j < 8; j++)
                b[j] = (short)f2bf(ws[OFF_Wd1 + (32 * c + 8 * quad + j) * 64 + 16 * t + m]);
            bfr[c][t] = b;
        }
    float w2[4], b1v[4];
#pragma unroll
    for (int t = 0; t < 4; t++) {
        w2[t]  = ws[OFF_Wd2 + 16 * t + m];
        b1v[t] = ws[OFF_bd1 + 16 * t + m];
    }
    float b2 = ws[OFF_bd2];

    int tile0 = (blockIdx.x * 4 + wv) * DEC_TPW;
    for (int i = 0; i < DEC_TPW; i++) {
        int tile = tile0 + i;
        if (tile >= DEC_TILES) break;
        int e0 = tile * 16;
        int s = src[e0 + m];
        int d = dst[e0 + m];
        f32x4 acc[4] = {f32x4{0,0,0,0}, f32x4{0,0,0,0}, f32x4{0,0,0,0}, f32x4{0,0,0,0}};
#pragma unroll
        for (int c = 0; c < 4; c++) {
            int row = (c < 2) ? s : d;
            const bf16x8* ap = reinterpret_cast<const bf16x8*>(
                hbf + (size_t)row * 64 + (c & 1) * 32 + 8 * quad);
            bf16x8 a = *ap;
#pragma unroll
            for (int t = 0; t < 4; t++)
                acc[t] = __builtin_amdgcn_mfma_f32_16x16x32_bf16(a, bfr[c][t], acc[t], 0, 0, 0);
        }
        float sums[4];
#pragma unroll
        for (int r = 0; r < 4; r++) {
            float sv = 0.0f;
#pragma unroll
            for (int t = 0; t < 4; t++) {
                float v = acc[t][r] + b1v[t];
                float h = v / (1.0f + __expf(-v));
                sv = fmaf(h, w2[t], sv);
            }
#pragma unroll
            for (int msk = 8; msk >= 1; msk >>= 1)
                sv += __shfl_xor(sv, msk, 64);
            sums[r] = sv;
        }
        if (m == 0) {
            int ebase = e0 + 4 * quad;
#pragma unroll
            for (int r = 0; r < 4; r++) out[ebase + r] = sums[r] + b2;
        }
    }
}

extern "C" void kernel_launch(void* const* d_in, const int* in_sizes, int n_in,
                              void* d_out, int out_size, void* d_ws, size_t ws_size,
                              hipStream_t stream) {
    if (n_in < 18) return;
    const void* x              = d_in[0];
    const int* edge_index      = (const int*)d_in[1];
    const int* full_edge_index = (const int*)d_in[2];
    const int* tsteps          = (const int*)d_in[3];
    float* ws = (float*)d_ws;
    float* out = (float*)d_out;

    int*   iws   = (int*)d_ws;
    int*   cnt   = iws + OFF_CNT;
    int*   ptr   = iws + OFF_PTR;
    int*   cur   = iws + OFF_CUR;
    int*   elist = iws + OFF_ELIST;
    unsigned short* zbf  = (unsigned short*)(ws + OFF_ZBF);
    unsigned short* henc = (unsigned short*)(ws + OFF_HENC);

    CvtArgs ca;
    for (int i = 0; i < 14; i++) ca.src[i] = d_in[4 + i];

    // dtype flag, weights -> fp32, t_emb table
    k_detect<<<1, 256, 0, stream>>>((const unsigned short*)d_in[4], ws);
    k_cvt<<<(W_TOTAL + 255) / 256, 256, 0, stream>>>(ca, ws);
    k_temb<<<T_STEPS, 64, 0, stream>>>(ws);

    // embedder (writes h_embed: fp32 -> A, fp32 -> out)
    k_embed<<<N_NODES / 8, 64, 0, stream>>>(x, tsteps, ws, out + E_FULL);

    // CSR build (by dst) + dinv
    hipMemsetAsync(cnt, 0, (size_t)N_NODES * 4, stream);
    k_count<<<(E_MSG + 255) / 256, 256, 0, stream>>>(edge_index + E_MSG, cnt);
    k_scan<<<1, 1024, 0, stream>>>(cnt, ptr, cur, ws + OFF_DINV);
    k_fill<<<(E_MSG + 255) / 256, 256, 0, stream>>>(edge_index, edge_index + E_MSG,
                                                    cur, elist);

    // GCN layer 0: A(h_embed) -> zbf -> gather -> A(h1, relu)
    k_lin<<<N_NODES / 16, 64, 0, stream>>>(ws + OFF_A, ws + OFF_Wc0, ws + OFF_DINV, zbf);
    k_gather<true, false><<<N_NODES / 4, 256, 0, stream>>>(
        zbf, ptr, elist, ws + OFF_DINV, ws + OFF_bc0, ws + OFF_A, nullptr, nullptr);

    // GCN layer 1: A(h1) -> zbf -> gather -> {out fp32, henc bf16}
    k_lin<<<N_NODES / 16, 64, 0, stream>>>(ws + OFF_A, ws + OFF_Wc1, ws + OFF_DINV, zbf);
    k_gather<false, true><<<N_NODES / 4, 256, 0, stream>>>(
        zbf, ptr, elist, ws + OFF_DINV, ws + OFF_bc1, nullptr, henc,
        out + E_FULL + (size_t)N_NODES * 64);

    // decoder (MFMA)
    int dec_blocks = (DEC_TILES + 4 * DEC_TPW - 1) / (4 * DEC_TPW);
    k_dec<<<dec_blocks, 256, 0, stream>>>(full_edge_index, full_edge_index + E_FULL,
                                          henc, ws, out);
}

// Round 6
// 468.591 us; speedup vs baseline: 2.7746x; 1.2754x over previous
//
#include <hip/hip_runtime.h>
#include <hip/hip_bf16.h>
#include <math.h>

#define N_NODES 50000
#define E_MSG   800000
#define E_FULL  1000000
#define IN_C    128
#define H_C     64
#define T_STEPS 128

// ---- workspace layout (in floats) ----
#define OFF_Win   0
#define OFF_bin   8192
#define OFF_Wt1   8256
#define OFF_bt1   24640
#define OFF_Wt2   24896
#define OFF_bt2   41280
#define OFF_Wc0   41344
#define OFF_bc0   45440
#define OFF_Wc1   45504
#define OFF_bc1   49600
#define OFF_Wd1   49664
#define OFF_bd1   57856
#define OFF_Wd2   57920
#define OFF_bd2   57984
#define W_TOTAL   57985
#define OFF_FLAG  58000                 // 1.0f if float inputs are fp32, 0.0f if bf16
#define OFF_BSUM  58016                 // 256 ints (block sums for hierarchical scan)
#define OFF_TEMB  65536                 // 128*64
#define OFF_DINV  73728                 // 50000 floats
#define OFF_CNT   123904                // 50000 ints (in-degree histogram)
#define OFF_PTR   173904                // 50001 ints (CSR row pointers, by dst)
#define OFF_CUR   223936                // 50000 ints (fill cursors)
#define OFF_ELIST 274432                // 800000 ints (src node per CSR slot)
#define OFF_A     1074432               // 3.2M floats (h_embed -> h1, fp32)
#define OFF_ZBF   4274432               // 1.6M floats = 3.2M bf16 (z table)
#define OFF_HENC  5874432               // 1.6M floats = 3.2M bf16 (h_enc for decoder)
// total: 7,474,432 floats = 29.9 MB

#define SCAN_NB   ((N_NODES + 255) / 256)   // 196 blocks

typedef __attribute__((ext_vector_type(8))) short bf16x8;
typedef __attribute__((ext_vector_type(4))) float f32x4;

static __device__ __forceinline__ float bf2f(unsigned short u) {
    return __uint_as_float(((unsigned)u) << 16);
}
static __device__ __forceinline__ unsigned short f2bf(float f) {
    unsigned u = __float_as_uint(f);
    unsigned r = (u + 0x7fffu + ((u >> 16) & 1u)) >> 16;
    return (unsigned short)r;
}

// ---------------- input dtype detector ----------------
__global__ void k_detect(const unsigned short* __restrict__ w, float* __restrict__ ws) {
    __shared__ int cnt;
    if (threadIdx.x == 0) cnt = 0;
    __syncthreads();
    int big = 0;
    for (int i = threadIdx.x; i < 2048; i += 256) {
        float v = bf2f(w[2 * i]);
        if (fabsf(v) > 0.5f) big++;
    }
    atomicAdd(&cnt, big);
    __syncthreads();
    if (threadIdx.x == 0) ws[OFF_FLAG] = (cnt > 64) ? 1.0f : 0.0f;
}

// ---------------- weight conversion -> fp32, packed ----------------
struct CvtArgs { const void* src[14]; };

__global__ void k_cvt(CvtArgs a, float* ws) {
    int t = blockIdx.x * 256 + threadIdx.x;
    if (t >= W_TOTAL) return;
    const int starts[14] = {OFF_Win, OFF_bin, OFF_Wt1, OFF_bt1, OFF_Wt2, OFF_bt2,
                            OFF_Wc0, OFF_bc0, OFF_Wc1, OFF_bc1, OFF_Wd1, OFF_bd1,
                            OFF_Wd2, OFF_bd2};
    int seg = 0;
#pragma unroll
    for (int i = 1; i < 14; i++)
        if (t >= starts[i]) seg = i;
    int off = t - starts[seg];
    bool f32 = (ws[OFF_FLAG] != 0.0f);
    float v = f32 ? ((const float*)a.src[seg])[off]
                  : bf2f(((const unsigned short*)a.src[seg])[off]);
    ws[t] = v;
}

// ---------------- t_emb table: only 128 distinct timesteps ----------------
__global__ void __launch_bounds__(64) k_temb(float* ws) {
    const float* Wt1 = ws + OFF_Wt1;
    const float* bt1 = ws + OFF_bt1;
    const float* Wt2 = ws + OFF_Wt2;
    const float* bt2 = ws + OFF_bt2;
    float* temb = ws + OFF_TEMB;
    int t = blockIdx.x;      // timestep 0..127
    int j = threadIdx.x;     // channel 0..63

    __shared__ float pe[64];
    __shared__ float us[256];

    float xt = (float)t * (4000.0f / 128.0f);
    float sc = -logf(10000.0f) / 31.0f;     // half-1 = 31
    int idx = j & 31;
    float fr = __expf((float)idx * sc);
    float ang = xt * fr;
    pe[j] = (j < 32) ? sinf(ang) : cosf(ang);
    __syncthreads();

    float u[4];
#pragma unroll
    for (int q = 0; q < 4; q++) u[q] = bt1[q * 64 + j];
    for (int k = 0; k < 64; k++) {
        float p = pe[k];
#pragma unroll
        for (int q = 0; q < 4; q++)
            u[q] = fmaf(p, Wt1[k * 256 + q * 64 + j], u[q]);
    }
#pragma unroll
    for (int q = 0; q < 4; q++) {
        float uu = u[q];
        us[q * 64 + j] = uu / (1.0f + __expf(-uu));   // silu
    }
    __syncthreads();

    float acc = bt2[j];
    for (int k = 0; k < 256; k++)
        acc = fmaf(us[k], Wt2[k * 64 + j], acc);
    temb[t * 64 + j] = acc;
}

// ---------------- embedder: h_embed = x @ W_in + b_in + temb[t] ----------------
__global__ void __launch_bounds__(64) k_embed(const void* __restrict__ xraw,
                                              const int* __restrict__ tsteps,
                                              float* __restrict__ ws,
                                              float* __restrict__ out_hembed) {
    int j = threadIdx.x;
    const float* Win = ws + OFF_Win;
    float wcol[128];
#pragma unroll
    for (int k = 0; k < 128; k++) wcol[k] = Win[k * 64 + j];
    float bj = ws[OFF_bin + j];
    const float* temb = ws + OFF_TEMB;
    float* A = ws + OFF_A;
    bool f32 = (ws[OFF_FLAG] != 0.0f);

    for (int i = 0; i < 8; i++) {
        int n = blockIdx.x * 8 + i;
        int tn = tsteps[n];
        float acc = bj + temb[tn * 64 + j];
        if (f32) {
            const float4* xr = reinterpret_cast<const float4*>((const float*)xraw + (size_t)n * 128);
#pragma unroll
            for (int q = 0; q < 32; q++) {
                float4 v = xr[q];
                acc = fmaf(v.x, wcol[q * 4 + 0], acc);
                acc = fmaf(v.y, wcol[q * 4 + 1], acc);
                acc = fmaf(v.z, wcol[q * 4 + 2], acc);
                acc = fmaf(v.w, wcol[q * 4 + 3], acc);
            }
        } else {
            const uint4* xr = reinterpret_cast<const uint4*>((const unsigned short*)xraw + (size_t)n * 128);
#pragma unroll
            for (int q = 0; q < 8; q++) {
                uint4 vv = xr[q];
                unsigned d0 = vv.x, d1 = vv.y, d2 = vv.z, d3 = vv.w;
                int k = q * 8;
                acc = fmaf(__uint_as_float(d0 << 16),         wcol[k + 0], acc);
                acc = fmaf(__uint_as_float(d0 & 0xffff0000u), wcol[k + 1], acc);
                acc = fmaf(__uint_as_float(d1 << 16),         wcol[k + 2], acc);
                acc = fmaf(__uint_as_float(d1 & 0xffff0000u), wcol[k + 3], acc);
                acc = fmaf(__uint_as_float(d2 << 16),         wcol[k + 4], acc);
                acc = fmaf(__uint_as_float(d2 & 0xffff0000u), wcol[k + 5], acc);
                acc = fmaf(__uint_as_float(d3 << 16),         wcol[k + 6], acc);
                acc = fmaf(__uint_as_float(d3 & 0xffff0000u), wcol[k + 7], acc);
            }
        }
        A[(size_t)n * 64 + j] = acc;
        out_hembed[(size_t)n * 64 + j] = acc;
    }
}

// ---------------- CSR build: count -> hierarchical scan -> fill ----------------
__global__ void k_count(const int* __restrict__ col, int* __restrict__ cnt) {
    int t = blockIdx.x * 256 + threadIdx.x;
    if (t < E_MSG) atomicAdd(&cnt[col[t]], 1);
}

// phase 1: per-block (256 nodes) sums
__global__ void __launch_bounds__(256) k_scan1(const int* __restrict__ cnt,
                                               int* __restrict__ bsum) {
    __shared__ int s[256];
    int n = blockIdx.x * 256 + threadIdx.x;
    s[threadIdx.x] = (n < N_NODES) ? cnt[n] : 0;
    __syncthreads();
    for (int off = 128; off > 0; off >>= 1) {
        if (threadIdx.x < off) s[threadIdx.x] += s[threadIdx.x + off];
        __syncthreads();
    }
    if (threadIdx.x == 0) bsum[blockIdx.x] = s[0];
}

// phase 2: single block, exclusive scan of the 196 block sums
__global__ void __launch_bounds__(256) k_scan2(int* __restrict__ bsum,
                                               int* __restrict__ ptr) {
    __shared__ int s[256];
    int t = threadIdx.x;
    int v = (t < SCAN_NB) ? bsum[t] : 0;
    s[t] = v;
    __syncthreads();
    for (int off = 1; off < 256; off <<= 1) {
        int u = (t >= off) ? s[t - off] : 0;
        __syncthreads();
        s[t] += u;
        __syncthreads();
    }
    if (t < SCAN_NB) bsum[t] = s[t] - v;      // exclusive
    if (t == 0) ptr[N_NODES] = E_MSG;
}

// phase 3: intra-block exclusive scan + block offset; write ptr/cur/dinv
__global__ void __launch_bounds__(256) k_scan3(const int* __restrict__ cnt,
                                               const int* __restrict__ bsum,
                                               int* __restrict__ ptr,
                                               int* __restrict__ cur,
                                               float* __restrict__ dinv) {
    __shared__ int s[256];
    int t = threadIdx.x;
    int n = blockIdx.x * 256 + t;
    int v = (n < N_NODES) ? cnt[n] : 0;
    s[t] = v;
    __syncthreads();
    for (int off = 1; off < 256; off <<= 1) {
        int u = (t >= off) ? s[t - off] : 0;
        __syncthreads();
        s[t] += u;
        __syncthreads();
    }
    if (n < N_NODES) {
        int p = bsum[blockIdx.x] + s[t] - v;
        ptr[n] = p;
        cur[n] = p;
        dinv[n] = rsqrtf((float)v + 1.0f);
    }
}

__global__ void k_fill(const int* __restrict__ row, const int* __restrict__ col,
                       int* __restrict__ cur, int* __restrict__ elist) {
    int t = blockIdx.x * 256 + threadIdx.x;
    if (t < E_MSG) {
        int c = col[t];
        int pos = atomicAdd(&cur[c], 1);
        elist[pos] = row[t];
    }
}

// ---------------- GCN linear: zbf = bf16((h @ W) * dinv) ----------------
__global__ void __launch_bounds__(64) k_lin(const float* __restrict__ hin,
                                            const float* __restrict__ W,
                                            const float* __restrict__ dinv,
                                            unsigned short* __restrict__ zbf) {
    int j = threadIdx.x;
    float wcol[64];
#pragma unroll
    for (int k = 0; k < 64; k++) wcol[k] = W[k * 64 + j];

    for (int i = 0; i < 16; i++) {
        int n = blockIdx.x * 16 + i;
        const float4* hr = reinterpret_cast<const float4*>(hin + (size_t)n * 64);
        float acc = 0.0f;
#pragma unroll
        for (int q = 0; q < 16; q++) {
            float4 h4 = hr[q];
            acc = fmaf(h4.x, wcol[q * 4 + 0], acc);
            acc = fmaf(h4.y, wcol[q * 4 + 1], acc);
            acc = fmaf(h4.z, wcol[q * 4 + 2], acc);
            acc = fmaf(h4.w, wcol[q * 4 + 3], acc);
        }
        zbf[(size_t)n * 64 + j] = f2bf(acc * dinv[n]);
    }
}

// ---------------- fused gather + finalize ----------------
template <bool RELU, bool WRITE_OUT>
__global__ void __launch_bounds__(256) k_gather(const unsigned short* __restrict__ zbf,
                                                const int* __restrict__ ptr,
                                                const int* __restrict__ elist,
                                                const float* __restrict__ dinv,
                                                const float* __restrict__ bias,
                                                float* __restrict__ hout,
                                                unsigned short* __restrict__ hencbf,
                                                float* __restrict__ ofp) {
    int n = blockIdx.x * 4 + (threadIdx.x >> 6);
    int j = threadIdx.x & 63;
    int base = ptr[n];
    int end  = ptr[n + 1];
    float sum = bf2f(zbf[(size_t)n * 64 + j]);   // self-loop
    int k = base;
    for (; k + 4 <= end; k += 4) {
        int r0 = elist[k], r1 = elist[k + 1], r2 = elist[k + 2], r3 = elist[k + 3];
        float v0 = bf2f(zbf[(size_t)r0 * 64 + j]);
        float v1 = bf2f(zbf[(size_t)r1 * 64 + j]);
        float v2 = bf2f(zbf[(size_t)r2 * 64 + j]);
        float v3 = bf2f(zbf[(size_t)r3 * 64 + j]);
        sum += (v0 + v1) + (v2 + v3);
    }
    for (; k < end; k++)
        sum += bf2f(zbf[(size_t)elist[k] * 64 + j]);
    float v = dinv[n] * sum + bias[j];
    if (RELU) v = fmaxf(v, 0.0f);
    size_t t = (size_t)n * 64 + j;
    if (WRITE_OUT) {
        ofp[t] = v;
        hencbf[t] = f2bf(v);
    } else {
        hout[t] = v;
    }
}

// ---------------- edge decoder (MFMA bf16) ----------------
#define DEC_TPW 8
#define DEC_TILES (E_FULL / 16)

__global__ void __launch_bounds__(256) k_dec(const int* __restrict__ src,
                                             const int* __restrict__ dst,
                                             const unsigned short* __restrict__ hbf,
                                             const float* __restrict__ ws,
                                             float* __restrict__ out) {
    int lane = threadIdx.x & 63;
    int wv = threadIdx.x >> 6;
    int m = lane & 15;
    int quad = lane >> 4;

    bf16x8 bfr[4][4];
#pragma unroll
    for (int c = 0; c < 4; c++)
#pragma unroll
        for (int t = 0; t < 4; t++) {
            bf16x8 b;
#pragma unroll
            for (int j = 0; j < 8; j++)
                b[j] = (short)f2bf(ws[OFF_Wd1 + (32 * c + 8 * quad + j) * 64 + 16 * t + m]);
            bfr[c][t] = b;
        }
    float w2[4], b1v[4];
#pragma unroll
    for (int t = 0; t < 4; t++) {
        w2[t]  = ws[OFF_Wd2 + 16 * t + m];
        b1v[t] = ws[OFF_bd1 + 16 * t + m];
    }
    float b2 = ws[OFF_bd2];

    int tile0 = (blockIdx.x * 4 + wv) * DEC_TPW;
    for (int i = 0; i < DEC_TPW; i++) {
        int tile = tile0 + i;
        if (tile >= DEC_TILES) break;
        int e0 = tile * 16;
        int s = src[e0 + m];
        int d = dst[e0 + m];
        f32x4 acc[4] = {f32x4{0,0,0,0}, f32x4{0,0,0,0}, f32x4{0,0,0,0}, f32x4{0,0,0,0}};
#pragma unroll
        for (int c = 0; c < 4; c++) {
            int row = (c < 2) ? s : d;
            const bf16x8* ap = reinterpret_cast<const bf16x8*>(
                hbf + (size_t)row * 64 + (c & 1) * 32 + 8 * quad);
            bf16x8 a = *ap;
#pragma unroll
            for (int t = 0; t < 4; t++)
                acc[t] = __builtin_amdgcn_mfma_f32_16x16x32_bf16(a, bfr[c][t], acc[t], 0, 0, 0);
        }
        float sums[4];
#pragma unroll
        for (int r = 0; r < 4; r++) {
            float sv = 0.0f;
#pragma unroll
            for (int t = 0; t < 4; t++) {
                float v = acc[t][r] + b1v[t];
                float h = v / (1.0f + __expf(-v));
                sv = fmaf(h, w2[t], sv);
            }
#pragma unroll
            for (int msk = 8; msk >= 1; msk >>= 1)
                sv += __shfl_xor(sv, msk, 64);
            sums[r] = sv;
        }
        if (m == 0) {
            int ebase = e0 + 4 * quad;
#pragma unroll
            for (int r = 0; r < 4; r++) out[ebase + r] = sums[r] + b2;
        }
    }
}

extern "C" void kernel_launch(void* const* d_in, const int* in_sizes, int n_in,
                              void* d_out, int out_size, void* d_ws, size_t ws_size,
                              hipStream_t stream) {
    if (n_in < 18) return;
    const void* x              = d_in[0];
    const int* edge_index      = (const int*)d_in[1];
    const int* full_edge_index = (const int*)d_in[2];
    const int* tsteps          = (const int*)d_in[3];
    float* ws = (float*)d_ws;
    float* out = (float*)d_out;

    int*   iws   = (int*)d_ws;
    int*   bsum  = iws + OFF_BSUM;
    int*   cnt   = iws + OFF_CNT;
    int*   ptr   = iws + OFF_PTR;
    int*   cur   = iws + OFF_CUR;
    int*   elist = iws + OFF_ELIST;
    unsigned short* zbf  = (unsigned short*)(ws + OFF_ZBF);
    unsigned short* henc = (unsigned short*)(ws + OFF_HENC);

    CvtArgs ca;
    for (int i = 0; i < 14; i++) ca.src[i] = d_in[4 + i];

    // dtype flag, weights -> fp32, t_emb table
    k_detect<<<1, 256, 0, stream>>>((const unsigned short*)d_in[4], ws);
    k_cvt<<<(W_TOTAL + 255) / 256, 256, 0, stream>>>(ca, ws);
    k_temb<<<T_STEPS, 64, 0, stream>>>(ws);

    // embedder (writes h_embed: fp32 -> A, fp32 -> out)
    k_embed<<<N_NODES / 8, 64, 0, stream>>>(x, tsteps, ws, out + E_FULL);

    // CSR build (by dst) + dinv, hierarchical scan
    hipMemsetAsync(cnt, 0, (size_t)N_NODES * 4, stream);
    k_count<<<(E_MSG + 255) / 256, 256, 0, stream>>>(edge_index + E_MSG, cnt);
    k_scan1<<<SCAN_NB, 256, 0, stream>>>(cnt, bsum);
    k_scan2<<<1, 256, 0, stream>>>(bsum, ptr);
    k_scan3<<<SCAN_NB, 256, 0, stream>>>(cnt, bsum, ptr, cur, ws + OFF_DINV);
    k_fill<<<(E_MSG + 255) / 256, 256, 0, stream>>>(edge_index, edge_index + E_MSG,
                                                    cur, elist);

    // GCN layer 0: A(h_embed) -> zbf -> gather -> A(h1, relu)
    k_lin<<<N_NODES / 16, 64, 0, stream>>>(ws + OFF_A, ws + OFF_Wc0, ws + OFF_DINV, zbf);
    k_gather<true, false><<<N_NODES / 4, 256, 0, stream>>>(
        zbf, ptr, elist, ws + OFF_DINV, ws + OFF_bc0, ws + OFF_A, nullptr, nullptr);

    // GCN layer 1: A(h1) -> zbf -> gather -> {out fp32, henc bf16}
    k_lin<<<N_NODES / 16, 64, 0, stream>>>(ws + OFF_A, ws + OFF_Wc1, ws + OFF_DINV, zbf);
    k_gather<false, true><<<N_NODES / 4, 256, 0, stream>>>(
        zbf, ptr, elist, ws + OFF_DINV, ws + OFF_bc1, nullptr, henc,
        out + E_FULL + (size_t)N_NODES * 64);

    // decoder (MFMA)
    int dec_blocks = (DEC_TILES + 4 * DEC_TPW - 1) / (4 * DEC_TPW);
    k_dec<<<dec_blocks, 256, 0, stream>>>(full_edge_index, full_edge_index + E_FULL,
                                          henc, ws, out);
}

// Round 7
// 406.852 us; speedup vs baseline: 3.1956x; 1.1517x over previous
//
#include <hip/hip_runtime.h>
#include <hip/hip_bf16.h>
#include <math.h>

#define N_NODES 50000
#define E_MSG   800000
#define E_FULL  1000000
#define IN_C    128
#define H_C     64
#define T_STEPS 128

// ---- workspace layout (in floats) ----
#define OFF_Win   0
#define OFF_bin   8192
#define OFF_Wt1   8256
#define OFF_bt1   24640
#define OFF_Wt2   24896
#define OFF_bt2   41280
#define OFF_Wc0   41344
#define OFF_bc0   45440
#define OFF_Wc1   45504
#define OFF_bc1   49600
#define OFF_Wd1   49664
#define OFF_bd1   57856
#define OFF_Wd2   57920
#define OFF_bd2   57984
#define W_TOTAL   57985
#define OFF_FLAG  58000                 // 1.0f if float inputs are fp32, 0.0f if bf16
#define OFF_BSUM  58016                 // 256 ints (block sums for hierarchical scan)
#define OFF_FWD1  58368                 // 4096 floats = 8192 bf16 (Wd1 MFMA frag table)
#define OFF_FWIN  62464                 // 4096 floats = 8192 bf16 (W_in MFMA frag table)
#define OFF_TEMB  66560                 // 128*64
#define OFF_DINV  74752                 // 50000 floats
#define OFF_CNT   124928                // 50000 ints (in-degree histogram)
#define OFF_PTR   174928                // 50001 ints (CSR row pointers, by dst)
#define OFF_CUR   224960                // 50000 ints (fill cursors)
#define OFF_ELIST 275456                // 800000 ints (src node per CSR slot)
#define OFF_A     1075456               // 3.2M floats (h_embed -> h1, fp32)
#define OFF_ZBF   4275456               // 1.6M floats = 3.2M bf16 (z table)
#define OFF_HENC  5875456               // 1.6M floats = 3.2M bf16 (h_enc for decoder)
// total: 7,475,456 floats = 29.9 MB

#define SCAN_NB   ((N_NODES + 255) / 256)   // 196 blocks

typedef __attribute__((ext_vector_type(8))) short bf16x8;
typedef __attribute__((ext_vector_type(4))) float f32x4;

static __device__ __forceinline__ float bf2f(unsigned short u) {
    return __uint_as_float(((unsigned)u) << 16);
}
static __device__ __forceinline__ unsigned short f2bf(float f) {
    unsigned u = __float_as_uint(f);
    unsigned r = (u + 0x7fffu + ((u >> 16) & 1u)) >> 16;
    return (unsigned short)r;
}

// ---------------- input dtype detector ----------------
__global__ void k_detect(const unsigned short* __restrict__ w, float* __restrict__ ws) {
    __shared__ int cnt;
    if (threadIdx.x == 0) cnt = 0;
    __syncthreads();
    int big = 0;
    for (int i = threadIdx.x; i < 2048; i += 256) {
        float v = bf2f(w[2 * i]);
        if (fabsf(v) > 0.5f) big++;
    }
    atomicAdd(&cnt, big);
    __syncthreads();
    if (threadIdx.x == 0) ws[OFF_FLAG] = (cnt > 64) ? 1.0f : 0.0f;
}

// ---------------- weight conversion -> fp32, packed ----------------
struct CvtArgs { const void* src[14]; };

__global__ void k_cvt(CvtArgs a, float* ws) {
    int t = blockIdx.x * 256 + threadIdx.x;
    if (t >= W_TOTAL) return;
    const int starts[14] = {OFF_Win, OFF_bin, OFF_Wt1, OFF_bt1, OFF_Wt2, OFF_bt2,
                            OFF_Wc0, OFF_bc0, OFF_Wc1, OFF_bc1, OFF_Wd1, OFF_bd1,
                            OFF_Wd2, OFF_bd2};
    int seg = 0;
#pragma unroll
    for (int i = 1; i < 14; i++)
        if (t >= starts[i]) seg = i;
    int off = t - starts[seg];
    bool f32 = (ws[OFF_FLAG] != 0.0f);
    float v = f32 ? ((const float*)a.src[seg])[off]
                  : bf2f(((const unsigned short*)a.src[seg])[off]);
    ws[t] = v;
}

// ---------------- MFMA B-fragment tables for Wd1 / W_in ----------------
// frag idx = (c*4+t)*512 + lane*8 + j  ->  W[(32c + 8*quad + j)][16t + m]
__global__ void __launch_bounds__(256) k_prep(float* ws) {
    unsigned short* fd = (unsigned short*)(ws + OFF_FWD1);
    unsigned short* fi = (unsigned short*)(ws + OFF_FWIN);
    for (int idx = threadIdx.x; idx < 8192; idx += 256) {
        int j = idx & 7;
        int lane = (idx >> 3) & 63;
        int ct = idx >> 9;               // 0..15
        int c = ct >> 2, t = ct & 3;
        int m = lane & 15, q = lane >> 4;
        int krow = 32 * c + 8 * q + j;
        int col = 16 * t + m;
        fd[idx] = f2bf(ws[OFF_Wd1 + krow * 64 + col]);
        fi[idx] = f2bf(ws[OFF_Win + krow * 64 + col]);
    }
}

// ---------------- t_emb table: only 128 distinct timesteps ----------------
__global__ void __launch_bounds__(64) k_temb(float* ws) {
    const float* Wt1 = ws + OFF_Wt1;
    const float* bt1 = ws + OFF_bt1;
    const float* Wt2 = ws + OFF_Wt2;
    const float* bt2 = ws + OFF_bt2;
    float* temb = ws + OFF_TEMB;
    int t = blockIdx.x;      // timestep 0..127
    int j = threadIdx.x;     // channel 0..63

    __shared__ float pe[64];
    __shared__ float us[256];

    float xt = (float)t * (4000.0f / 128.0f);
    float sc = -logf(10000.0f) / 31.0f;     // half-1 = 31
    int idx = j & 31;
    float fr = __expf((float)idx * sc);
    float ang = xt * fr;
    pe[j] = (j < 32) ? sinf(ang) : cosf(ang);
    __syncthreads();

    float u[4];
#pragma unroll
    for (int q = 0; q < 4; q++) u[q] = bt1[q * 64 + j];
    for (int k = 0; k < 64; k++) {
        float p = pe[k];
#pragma unroll
        for (int q = 0; q < 4; q++)
            u[q] = fmaf(p, Wt1[k * 256 + q * 64 + j], u[q]);
    }
#pragma unroll
    for (int q = 0; q < 4; q++) {
        float uu = u[q];
        us[q * 64 + j] = uu / (1.0f + __expf(-uu));   // silu
    }
    __syncthreads();

    float acc = bt2[j];
    for (int k = 0; k < 256; k++)
        acc = fmaf(us[k], Wt2[k * 64 + j], acc);
    temb[t * 64 + j] = acc;
}

// ---------------- embedder (MFMA): h_embed = x @ W_in + b_in + temb[t] ----------
// wave = 16-node tile. A[m=lane&15][k=quad*8+j] from x row n0+m (bf16-cast);
// C: node = quad*4+reg, ch = 16t + (lane&15).
__global__ void __launch_bounds__(256) k_embed(const void* __restrict__ xraw,
                                               const int* __restrict__ tsteps,
                                               float* __restrict__ ws,
                                               float* __restrict__ out_hembed) {
    int lane = threadIdx.x & 63;
    int wv = threadIdx.x >> 6;
    int m = lane & 15, quad = lane >> 4;
    int wid = blockIdx.x * 4 + wv;
    if (wid >= N_NODES / 16) return;
    int n0 = wid * 16;

    const unsigned short* fw = (const unsigned short*)(ws + OFF_FWIN);
    bf16x8 bfr[4][4];
#pragma unroll
    for (int c = 0; c < 4; c++)
#pragma unroll
        for (int t = 0; t < 4; t++)
            bfr[c][t] = *reinterpret_cast<const bf16x8*>(fw + (c * 4 + t) * 512 + lane * 8);

    bool f32 = (ws[OFF_FLAG] != 0.0f);
    f32x4 acc[4] = {f32x4{0,0,0,0}, f32x4{0,0,0,0}, f32x4{0,0,0,0}, f32x4{0,0,0,0}};
#pragma unroll
    for (int c = 0; c < 4; c++) {
        bf16x8 a;
        if (f32) {
            const float* xp = (const float*)xraw + (size_t)(n0 + m) * 128 + 32 * c + 8 * quad;
            float4 v0 = *reinterpret_cast<const float4*>(xp);
            float4 v1 = *reinterpret_cast<const float4*>(xp + 4);
            a[0] = (short)f2bf(v0.x); a[1] = (short)f2bf(v0.y);
            a[2] = (short)f2bf(v0.z); a[3] = (short)f2bf(v0.w);
            a[4] = (short)f2bf(v1.x); a[5] = (short)f2bf(v1.y);
            a[6] = (short)f2bf(v1.z); a[7] = (short)f2bf(v1.w);
        } else {
            a = *reinterpret_cast<const bf16x8*>(
                (const unsigned short*)xraw + (size_t)(n0 + m) * 128 + 32 * c + 8 * quad);
        }
#pragma unroll
        for (int t = 0; t < 4; t++)
            acc[t] = __builtin_amdgcn_mfma_f32_16x16x32_bf16(a, bfr[c][t], acc[t], 0, 0, 0);
    }

    int tn[4];
#pragma unroll
    for (int r = 0; r < 4; r++) tn[r] = tsteps[n0 + 4 * quad + r];
    const float* temb = ws + OFF_TEMB;
    float* A = ws + OFF_A;
#pragma unroll
    for (int t = 0; t < 4; t++) {
        int ch = 16 * t + m;
        float bj = ws[OFF_bin + ch];
#pragma unroll
        for (int r = 0; r < 4; r++) {
            int node = n0 + 4 * quad + r;
            float v = acc[t][r] + bj + temb[tn[r] * 64 + ch];
            A[(size_t)node * 64 + ch] = v;
            out_hembed[(size_t)node * 64 + ch] = v;
        }
    }
}

// ---------------- CSR build: count -> hierarchical scan -> fill ----------------
__global__ void k_count(const int* __restrict__ col, int* __restrict__ cnt) {
    int t = blockIdx.x * 256 + threadIdx.x;
    if (t < E_MSG) atomicAdd(&cnt[col[t]], 1);
}

__global__ void __launch_bounds__(256) k_scan1(const int* __restrict__ cnt,
                                               int* __restrict__ bsum) {
    __shared__ int s[256];
    int n = blockIdx.x * 256 + threadIdx.x;
    s[threadIdx.x] = (n < N_NODES) ? cnt[n] : 0;
    __syncthreads();
    for (int off = 128; off > 0; off >>= 1) {
        if (threadIdx.x < off) s[threadIdx.x] += s[threadIdx.x + off];
        __syncthreads();
    }
    if (threadIdx.x == 0) bsum[blockIdx.x] = s[0];
}

__global__ void __launch_bounds__(256) k_scan2(int* __restrict__ bsum,
                                               int* __restrict__ ptr) {
    __shared__ int s[256];
    int t = threadIdx.x;
    int v = (t < SCAN_NB) ? bsum[t] : 0;
    s[t] = v;
    __syncthreads();
    for (int off = 1; off < 256; off <<= 1) {
        int u = (t >= off) ? s[t - off] : 0;
        __syncthreads();
        s[t] += u;
        __syncthreads();
    }
    if (t < SCAN_NB) bsum[t] = s[t] - v;      // exclusive
    if (t == 0) ptr[N_NODES] = E_MSG;
}

__global__ void __launch_bounds__(256) k_scan3(const int* __restrict__ cnt,
                                               const int* __restrict__ bsum,
                                               int* __restrict__ ptr,
                                               int* __restrict__ cur,
                                               float* __restrict__ dinv) {
    __shared__ int s[256];
    int t = threadIdx.x;
    int n = blockIdx.x * 256 + t;
    int v = (n < N_NODES) ? cnt[n] : 0;
    s[t] = v;
    __syncthreads();
    for (int off = 1; off < 256; off <<= 1) {
        int u = (t >= off) ? s[t - off] : 0;
        __syncthreads();
        s[t] += u;
        __syncthreads();
    }
    if (n < N_NODES) {
        int p = bsum[blockIdx.x] + s[t] - v;
        ptr[n] = p;
        cur[n] = p;
        dinv[n] = rsqrtf((float)v + 1.0f);
    }
}

__global__ void k_fill(const int* __restrict__ row, const int* __restrict__ col,
                       int* __restrict__ cur, int* __restrict__ elist) {
    int t = blockIdx.x * 256 + threadIdx.x;
    if (t < E_MSG) {
        int c = col[t];
        int pos = atomicAdd(&cur[c], 1);
        elist[pos] = row[t];
    }
}

// ---------------- GCN linear: zbf = bf16((h @ W) * dinv) ----------------
__global__ void __launch_bounds__(64) k_lin(const float* __restrict__ hin,
                                            const float* __restrict__ W,
                                            const float* __restrict__ dinv,
                                            unsigned short* __restrict__ zbf) {
    int j = threadIdx.x;
    float wcol[64];
#pragma unroll
    for (int k = 0; k < 64; k++) wcol[k] = W[k * 64 + j];

    for (int i = 0; i < 16; i++) {
        int n = blockIdx.x * 16 + i;
        const float4* hr = reinterpret_cast<const float4*>(hin + (size_t)n * 64);
        float acc = 0.0f;
#pragma unroll
        for (int q = 0; q < 16; q++) {
            float4 h4 = hr[q];
            acc = fmaf(h4.x, wcol[q * 4 + 0], acc);
            acc = fmaf(h4.y, wcol[q * 4 + 1], acc);
            acc = fmaf(h4.z, wcol[q * 4 + 2], acc);
            acc = fmaf(h4.w, wcol[q * 4 + 3], acc);
        }
        zbf[(size_t)n * 64 + j] = f2bf(acc * dinv[n]);
    }
}

// ---------------- fused gather + finalize ----------------
template <bool RELU, bool WRITE_OUT>
__global__ void __launch_bounds__(256) k_gather(const unsigned short* __restrict__ zbf,
                                                const int* __restrict__ ptr,
                                                const int* __restrict__ elist,
                                                const float* __restrict__ dinv,
                                                const float* __restrict__ bias,
                                                float* __restrict__ hout,
                                                unsigned short* __restrict__ hencbf,
                                                float* __restrict__ ofp) {
    int n = blockIdx.x * 4 + (threadIdx.x >> 6);
    int j = threadIdx.x & 63;
    int base = ptr[n];
    int end  = ptr[n + 1];
    float sum = bf2f(zbf[(size_t)n * 64 + j]);   // self-loop
    int k = base;
    for (; k + 8 <= end; k += 8) {
        int r0 = elist[k],     r1 = elist[k + 1], r2 = elist[k + 2], r3 = elist[k + 3];
        int r4 = elist[k + 4], r5 = elist[k + 5], r6 = elist[k + 6], r7 = elist[k + 7];
        float v0 = bf2f(zbf[(size_t)r0 * 64 + j]);
        float v1 = bf2f(zbf[(size_t)r1 * 64 + j]);
        float v2 = bf2f(zbf[(size_t)r2 * 64 + j]);
        float v3 = bf2f(zbf[(size_t)r3 * 64 + j]);
        float v4 = bf2f(zbf[(size_t)r4 * 64 + j]);
        float v5 = bf2f(zbf[(size_t)r5 * 64 + j]);
        float v6 = bf2f(zbf[(size_t)r6 * 64 + j]);
        float v7 = bf2f(zbf[(size_t)r7 * 64 + j]);
        sum += ((v0 + v1) + (v2 + v3)) + ((v4 + v5) + (v6 + v7));
    }
    for (; k + 4 <= end; k += 4) {
        int r0 = elist[k], r1 = elist[k + 1], r2 = elist[k + 2], r3 = elist[k + 3];
        float v0 = bf2f(zbf[(size_t)r0 * 64 + j]);
        float v1 = bf2f(zbf[(size_t)r1 * 64 + j]);
        float v2 = bf2f(zbf[(size_t)r2 * 64 + j]);
        float v3 = bf2f(zbf[(size_t)r3 * 64 + j]);
        sum += (v0 + v1) + (v2 + v3);
    }
    for (; k < end; k++)
        sum += bf2f(zbf[(size_t)elist[k] * 64 + j]);
    float v = dinv[n] * sum + bias[j];
    if (RELU) v = fmaxf(v, 0.0f);
    size_t t = (size_t)n * 64 + j;
    if (WRITE_OUT) {
        ofp[t] = v;
        hencbf[t] = f2bf(v);
    } else {
        hout[t] = v;
    }
}

// ---------------- edge decoder (MFMA bf16, software-pipelined) ----------------
#define DEC_TPW 8
#define DEC_TILES (E_FULL / 16)

__global__ void __launch_bounds__(256) k_dec(const int* __restrict__ src,
                                             const int* __restrict__ dst,
                                             const unsigned short* __restrict__ hbf,
                                             const float* __restrict__ ws,
                                             float* __restrict__ out) {
    int lane = threadIdx.x & 63;
    int wv = threadIdx.x >> 6;
    int m = lane & 15;
    int quad = lane >> 4;

    const unsigned short* fw = (const unsigned short*)(ws + OFF_FWD1);
    bf16x8 bfr[4][4];
#pragma unroll
    for (int c = 0; c < 4; c++)
#pragma unroll
        for (int t = 0; t < 4; t++)
            bfr[c][t] = *reinterpret_cast<const bf16x8*>(fw + (c * 4 + t) * 512 + lane * 8);

    float w2[4], b1v[4];
#pragma unroll
    for (int t = 0; t < 4; t++) {
        w2[t]  = ws[OFF_Wd2 + 16 * t + m];
        b1v[t] = ws[OFF_bd1 + 16 * t + m];
    }
    float b2 = ws[OFF_bd2];

    int tile0 = (blockIdx.x * 4 + wv) * DEC_TPW;
    // ---- pipeline prologue: indices for tiles 0,1; A-frags for tile 0 ----
    int tc = min(tile0, DEC_TILES - 1);
    int s0 = src[tc * 16 + m], d0 = dst[tc * 16 + m];
    tc = min(tile0 + 1, DEC_TILES - 1);
    int s1 = src[tc * 16 + m], d1 = dst[tc * 16 + m];
    bf16x8 A0[4];
#pragma unroll
    for (int c = 0; c < 4; c++) {
        int row = (c < 2) ? s0 : d0;
        A0[c] = *reinterpret_cast<const bf16x8*>(
            hbf + (size_t)row * 64 + (c & 1) * 32 + 8 * quad);
    }

    for (int i = 0; i < DEC_TPW; i++) {
        int tile = tile0 + i;
        // prefetch indices for tile i+2
        int t2 = min(tile0 + i + 2, DEC_TILES - 1);
        int s2 = src[t2 * 16 + m], d2 = dst[t2 * 16 + m];
        // prefetch A-frags for tile i+1 (indices loaded 1 iter ago)
        bf16x8 A1[4];
#pragma unroll
        for (int c = 0; c < 4; c++) {
            int row = (c < 2) ? s1 : d1;
            A1[c] = *reinterpret_cast<const bf16x8*>(
                hbf + (size_t)row * 64 + (c & 1) * 32 + 8 * quad);
        }
        // compute tile i
        f32x4 acc[4] = {f32x4{0,0,0,0}, f32x4{0,0,0,0}, f32x4{0,0,0,0}, f32x4{0,0,0,0}};
#pragma unroll
        for (int c = 0; c < 4; c++)
#pragma unroll
            for (int t = 0; t < 4; t++)
                acc[t] = __builtin_amdgcn_mfma_f32_16x16x32_bf16(A0[c], bfr[c][t], acc[t], 0, 0, 0);
        float sums[4];
#pragma unroll
        for (int r = 0; r < 4; r++) {
            float sv = 0.0f;
#pragma unroll
            for (int t = 0; t < 4; t++) {
                float v = acc[t][r] + b1v[t];
                float h = v / (1.0f + __expf(-v));
                sv = fmaf(h, w2[t], sv);
            }
#pragma unroll
            for (int msk = 8; msk >= 1; msk >>= 1)
                sv += __shfl_xor(sv, msk, 64);
            sums[r] = sv;
        }
        if (m == 0 && tile < DEC_TILES) {
            int ebase = tile * 16 + 4 * quad;
#pragma unroll
            for (int r = 0; r < 4; r++) out[ebase + r] = sums[r] + b2;
        }
        // shift pipeline
#pragma unroll
        for (int c = 0; c < 4; c++) A0[c] = A1[c];
        s1 = s2; d1 = d2;
    }
}

extern "C" void kernel_launch(void* const* d_in, const int* in_sizes, int n_in,
                              void* d_out, int out_size, void* d_ws, size_t ws_size,
                              hipStream_t stream) {
    if (n_in < 18) return;
    const void* x              = d_in[0];
    const int* edge_index      = (const int*)d_in[1];
    const int* full_edge_index = (const int*)d_in[2];
    const int* tsteps          = (const int*)d_in[3];
    float* ws = (float*)d_ws;
    float* out = (float*)d_out;

    int*   iws   = (int*)d_ws;
    int*   bsum  = iws + OFF_BSUM;
    int*   cnt   = iws + OFF_CNT;
    int*   ptr   = iws + OFF_PTR;
    int*   cur   = iws + OFF_CUR;
    int*   elist = iws + OFF_ELIST;
    unsigned short* zbf  = (unsigned short*)(ws + OFF_ZBF);
    unsigned short* henc = (unsigned short*)(ws + OFF_HENC);

    CvtArgs ca;
    for (int i = 0; i < 14; i++) ca.src[i] = d_in[4 + i];

    // dtype flag, weights -> fp32, frag tables, t_emb table
    k_detect<<<1, 256, 0, stream>>>((const unsigned short*)d_in[4], ws);
    k_cvt<<<(W_TOTAL + 255) / 256, 256, 0, stream>>>(ca, ws);
    k_prep<<<1, 256, 0, stream>>>(ws);
    k_temb<<<T_STEPS, 64, 0, stream>>>(ws);

    // embedder (MFMA; writes h_embed: fp32 -> A, fp32 -> out)
    k_embed<<<(N_NODES / 16 + 3) / 4, 256, 0, stream>>>(x, tsteps, ws, out + E_FULL);

    // CSR build (by dst) + dinv, hierarchical scan
    hipMemsetAsync(cnt, 0, (size_t)N_NODES * 4, stream);
    k_count<<<(E_MSG + 255) / 256, 256, 0, stream>>>(edge_index + E_MSG, cnt);
    k_scan1<<<SCAN_NB, 256, 0, stream>>>(cnt, bsum);
    k_scan2<<<1, 256, 0, stream>>>(bsum, ptr);
    k_scan3<<<SCAN_NB, 256, 0, stream>>>(cnt, bsum, ptr, cur, ws + OFF_DINV);
    k_fill<<<(E_MSG + 255) / 256, 256, 0, stream>>>(edge_index, edge_index + E_MSG,
                                                    cur, elist);

    // GCN layer 0: A(h_embed) -> zbf -> gather -> A(h1, relu)
    k_lin<<<N_NODES / 16, 64, 0, stream>>>(ws + OFF_A, ws + OFF_Wc0, ws + OFF_DINV, zbf);
    k_gather<true, false><<<N_NODES / 4, 256, 0, stream>>>(
        zbf, ptr, elist, ws + OFF_DINV, ws + OFF_bc0, ws + OFF_A, nullptr, nullptr);

    // GCN layer 1: A(h1) -> zbf -> gather -> {out fp32, henc bf16}
    k_lin<<<N_NODES / 16, 64, 0, stream>>>(ws + OFF_A, ws + OFF_Wc1, ws + OFF_DINV, zbf);
    k_gather<false, true><<<N_NODES / 4, 256, 0, stream>>>(
        zbf, ptr, elist, ws + OFF_DINV, ws + OFF_bc1, nullptr, henc,
        out + E_FULL + (size_t)N_NODES * 64);

    // decoder (MFMA, pipelined)
    int dec_blocks = (DEC_TILES + 4 * DEC_TPW - 1) / (4 * DEC_TPW);
    k_dec<<<dec_blocks, 256, 0, stream>>>(full_edge_index, full_edge_index + E_FULL,
                                          henc, ws, out);
}

// Round 8
// 345.032 us; speedup vs baseline: 3.7681x; 1.1792x over previous
//
#include <hip/hip_runtime.h>
#include <hip/hip_bf16.h>
#include <math.h>

#define N_NODES 50000
#define E_MSG   800000
#define E_FULL  1000000
#define IN_C    128
#define H_C     64
#define T_STEPS 128

// ---- workspace layout (in floats) ----
#define OFF_Win   0
#define OFF_bin   8192
#define OFF_Wt1   8256
#define OFF_bt1   24640
#define OFF_Wt2   24896
#define OFF_bt2   41280
#define OFF_Wc0   41344
#define OFF_bc0   45440
#define OFF_Wc1   45504
#define OFF_bc1   49600
#define OFF_Wd1   49664
#define OFF_bd1   57856
#define OFF_Wd2   57920
#define OFF_bd2   57984
#define W_TOTAL   57985
#define OFF_BSUM  58016                 // 256 ints
#define OFF_FWD1  58368                 // 8192 bf16 (Wd1 frag table, K=128)
#define OFF_FWIN  62464                 // 8192 bf16 (W_in frag table, K=128)
#define OFF_FWC0  66560                 // 4096 bf16 (Wc0 frag table, K=64)
#define OFF_FWC1  68608                 // 4096 bf16 (Wc1 frag table, K=64)
#define OFF_TEMB  70656                 // 128*64 floats
#define OFF_DINV  78848                 // 50000 floats
#define OFF_CNT   128848                // 50000 ints
#define OFF_PTR   178848                // 50001 ints
#define OFF_CUR   228864                // 50000 ints
#define OFF_ELIST 278864                // 800000 ints
#define OFF_A     1078864               // 3.2M floats (h1 fp32)
#define OFF_ZBF   4278864               // 3.2M bf16 (z table)
#define OFF_HENC  5878864               // 3.2M bf16 (h_enc)
// total 7,478,864 floats = 29.9 MB

#define SCAN_NB   ((N_NODES + 255) / 256)   // 196

typedef __attribute__((ext_vector_type(8))) short bf16x8;
typedef __attribute__((ext_vector_type(4))) float f32x4;

static __device__ __forceinline__ float bf2f(unsigned short u) {
    return __uint_as_float(((unsigned)u) << 16);
}
static __device__ __forceinline__ unsigned short f2bf(float f) {
    unsigned u = __float_as_uint(f);
    unsigned r = (u + 0x7fffu + ((u >> 16) & 1u)) >> 16;
    return (unsigned short)r;
}
// per-block input-dtype detection (bf16 vs fp32) from W_in's raw uint16s
static __device__ __forceinline__ bool detect_f32(const unsigned short* w, int* scnt) {
    if (threadIdx.x == 0) *scnt = 0;
    __syncthreads();
    int big = 0;
    for (int i = threadIdx.x; i < 2048; i += blockDim.x)
        if (fabsf(bf2f(w[2 * i])) > 0.5f) big++;
    atomicAdd(scnt, big);
    __syncthreads();
    return *scnt > 64;
}

// ---------------- weight conversion -> fp32, packed ----------------
struct CvtArgs { const void* src[14]; };

__global__ void k_cvt(CvtArgs a, float* ws) {
    __shared__ int scnt;
    bool f32 = detect_f32((const unsigned short*)a.src[0], &scnt);
    int t = blockIdx.x * 256 + threadIdx.x;
    if (t >= W_TOTAL) return;
    const int starts[14] = {OFF_Win, OFF_bin, OFF_Wt1, OFF_bt1, OFF_Wt2, OFF_bt2,
                            OFF_Wc0, OFF_bc0, OFF_Wc1, OFF_bc1, OFF_Wd1, OFF_bd1,
                            OFF_Wd2, OFF_bd2};
    int seg = 0;
#pragma unroll
    for (int i = 1; i < 14; i++)
        if (t >= starts[i]) seg = i;
    int off = t - starts[seg];
    ws[t] = f32 ? ((const float*)a.src[seg])[off]
                : bf2f(((const unsigned short*)a.src[seg])[off]);
}

// ---------------- MFMA B-fragment tables ----------------
// frag idx within table = (c*4+t)*512 + lane*8 + j -> W[(32c+8q+j)*64 + 16t+m]
__global__ void __launch_bounds__(256) k_prep(float* ws) {
    int idx = blockIdx.x * 256 + threadIdx.x;      // 0..24575
    unsigned short* dst;
    int srcw, local;
    if (idx < 8192)       { dst = (unsigned short*)(ws + OFF_FWD1); local = idx;         srcw = OFF_Wd1; }
    else if (idx < 16384) { dst = (unsigned short*)(ws + OFF_FWIN); local = idx - 8192;  srcw = OFF_Win; }
    else if (idx < 20480) { dst = (unsigned short*)(ws + OFF_FWC0); local = idx - 16384; srcw = OFF_Wc0; }
    else                  { dst = (unsigned short*)(ws + OFF_FWC1); local = idx - 20480; srcw = OFF_Wc1; }
    int j = local & 7;
    int lane = (local >> 3) & 63;
    int ct = local >> 9;
    int c = ct >> 2, t = ct & 3;
    int m = lane & 15, q = lane >> 4;
    dst[local] = f2bf(ws[srcw + (32 * c + 8 * q + j) * 64 + 16 * t + m]);
}

// ---------------- t_emb table ----------------
__global__ void __launch_bounds__(64) k_temb(float* ws) {
    const float* Wt1 = ws + OFF_Wt1;
    const float* bt1 = ws + OFF_bt1;
    const float* Wt2 = ws + OFF_Wt2;
    const float* bt2 = ws + OFF_bt2;
    float* temb = ws + OFF_TEMB;
    int t = blockIdx.x;
    int j = threadIdx.x;

    __shared__ float pe[64];
    __shared__ float us[256];

    float xt = (float)t * (4000.0f / 128.0f);
    float sc = -logf(10000.0f) / 31.0f;
    int idx = j & 31;
    float fr = __expf((float)idx * sc);
    float ang = xt * fr;
    pe[j] = (j < 32) ? sinf(ang) : cosf(ang);
    __syncthreads();

    float u[4];
#pragma unroll
    for (int q = 0; q < 4; q++) u[q] = bt1[q * 64 + j];
    for (int k = 0; k < 64; k++) {
        float p = pe[k];
#pragma unroll
        for (int q = 0; q < 4; q++)
            u[q] = fmaf(p, Wt1[k * 256 + q * 64 + j], u[q]);
    }
#pragma unroll
    for (int q = 0; q < 4; q++) {
        float uu = u[q];
        us[q * 64 + j] = uu * __builtin_amdgcn_rcpf(1.0f + __expf(-uu));
    }
    __syncthreads();

    float acc = bt2[j];
    for (int k = 0; k < 256; k++)
        acc = fmaf(us[k], Wt2[k * 64 + j], acc);
    temb[t * 64 + j] = acc;
}

// ---------------- embedder + fused GCN-linear-0 (MFMA x2) ----------------
// Stage 1: h_embed = x @ W_in + b_in + temb[t]   (write fp32 to d_out)
// Stage 2 (fused lin0): zbf0 = bf16((h_embed @ Wc0) * dinv)  via LDS transpose
__global__ void __launch_bounds__(256) k_embed(const void* __restrict__ xraw,
                                               const unsigned short* __restrict__ wdet,
                                               const int* __restrict__ tsteps,
                                               float* __restrict__ ws,
                                               float* __restrict__ out_hembed,
                                               unsigned short* __restrict__ zbf) {
    __shared__ int scnt;
    __shared__ unsigned short tl[4][16 * 64];
    bool f32 = detect_f32(wdet, &scnt);

    int lane = threadIdx.x & 63;
    int wv = threadIdx.x >> 6;
    int m = lane & 15, quad = lane >> 4;
    int wid = blockIdx.x * 4 + wv;
    if (wid > N_NODES / 16 - 1) wid = N_NODES / 16 - 1;   // clamp (dup work benign)
    int n0 = wid * 16;

    const unsigned short* fwin = (const unsigned short*)(ws + OFF_FWIN);
    const unsigned short* fwc0 = (const unsigned short*)(ws + OFF_FWC0);

    bf16x8 bI[4][4];
#pragma unroll
    for (int c = 0; c < 4; c++)
#pragma unroll
        for (int t = 0; t < 4; t++)
            bI[c][t] = *reinterpret_cast<const bf16x8*>(fwin + (c * 4 + t) * 512 + lane * 8);

    f32x4 acc[4] = {f32x4{0,0,0,0}, f32x4{0,0,0,0}, f32x4{0,0,0,0}, f32x4{0,0,0,0}};
#pragma unroll
    for (int c = 0; c < 4; c++) {
        bf16x8 a;
        if (f32) {
            const float* xp = (const float*)xraw + (size_t)(n0 + m) * 128 + 32 * c + 8 * quad;
            float4 v0 = *reinterpret_cast<const float4*>(xp);
            float4 v1 = *reinterpret_cast<const float4*>(xp + 4);
            a[0] = (short)f2bf(v0.x); a[1] = (short)f2bf(v0.y);
            a[2] = (short)f2bf(v0.z); a[3] = (short)f2bf(v0.w);
            a[4] = (short)f2bf(v1.x); a[5] = (short)f2bf(v1.y);
            a[6] = (short)f2bf(v1.z); a[7] = (short)f2bf(v1.w);
        } else {
            a = *reinterpret_cast<const bf16x8*>(
                (const unsigned short*)xraw + (size_t)(n0 + m) * 128 + 32 * c + 8 * quad);
        }
#pragma unroll
        for (int t = 0; t < 4; t++)
            acc[t] = __builtin_amdgcn_mfma_f32_16x16x32_bf16(a, bI[c][t], acc[t], 0, 0, 0);
    }

    int tn[4];
#pragma unroll
    for (int r = 0; r < 4; r++) tn[r] = tsteps[n0 + 4 * quad + r];
    const float* temb = ws + OFF_TEMB;
#pragma unroll
    for (int t = 0; t < 4; t++) {
        int ch = 16 * t + m;
        float bj = ws[OFF_bin + ch];
#pragma unroll
        for (int r = 0; r < 4; r++) {
            int node = n0 + 4 * quad + r;
            float v = acc[t][r] + bj + temb[tn[r] * 64 + ch];
            out_hembed[(size_t)node * 64 + ch] = v;
            tl[wv][(4 * quad + r) * 64 + ch] = f2bf(v);
        }
    }
    __syncthreads();   // all waves active (wid clamped) -> safe

    // stage 2: lin0 via MFMA on the LDS tile
    bf16x8 bC[2][4];
#pragma unroll
    for (int c = 0; c < 2; c++)
#pragma unroll
        for (int t = 0; t < 4; t++)
            bC[c][t] = *reinterpret_cast<const bf16x8*>(fwc0 + (c * 4 + t) * 512 + lane * 8);

    f32x4 az[4] = {f32x4{0,0,0,0}, f32x4{0,0,0,0}, f32x4{0,0,0,0}, f32x4{0,0,0,0}};
#pragma unroll
    for (int c = 0; c < 2; c++) {
        bf16x8 a2 = *reinterpret_cast<const bf16x8*>(&tl[wv][m * 64 + 32 * c + 8 * quad]);
#pragma unroll
        for (int t = 0; t < 4; t++)
            az[t] = __builtin_amdgcn_mfma_f32_16x16x32_bf16(a2, bC[c][t], az[t], 0, 0, 0);
    }
    const float* dinv = ws + OFF_DINV;
    float dv[4];
#pragma unroll
    for (int r = 0; r < 4; r++) dv[r] = dinv[n0 + 4 * quad + r];
#pragma unroll
    for (int t = 0; t < 4; t++) {
        int ch = 16 * t + m;
#pragma unroll
        for (int r = 0; r < 4; r++)
            zbf[(size_t)(n0 + 4 * quad + r) * 64 + ch] = f2bf(az[t][r] * dv[r]);
    }
}

// ---------------- GCN linear-1 (MFMA): zbf = bf16((h1 @ Wc1) * dinv) ----------
__global__ void __launch_bounds__(256) k_linm(const float* __restrict__ hin,
                                              const float* __restrict__ ws,
                                              unsigned short* __restrict__ zbf) {
    int lane = threadIdx.x & 63;
    int wv = threadIdx.x >> 6;
    int m = lane & 15, quad = lane >> 4;
    int wid = blockIdx.x * 4 + wv;
    if (wid > N_NODES / 16 - 1) wid = N_NODES / 16 - 1;
    int n0 = wid * 16;

    const unsigned short* fwc1 = (const unsigned short*)(ws + OFF_FWC1);
    bf16x8 bC[2][4];
#pragma unroll
    for (int c = 0; c < 2; c++)
#pragma unroll
        for (int t = 0; t < 4; t++)
            bC[c][t] = *reinterpret_cast<const bf16x8*>(fwc1 + (c * 4 + t) * 512 + lane * 8);

    f32x4 az[4] = {f32x4{0,0,0,0}, f32x4{0,0,0,0}, f32x4{0,0,0,0}, f32x4{0,0,0,0}};
#pragma unroll
    for (int c = 0; c < 2; c++) {
        const float* xp = hin + (size_t)(n0 + m) * 64 + 32 * c + 8 * quad;
        float4 v0 = *reinterpret_cast<const float4*>(xp);
        float4 v1 = *reinterpret_cast<const float4*>(xp + 4);
        bf16x8 a;
        a[0] = (short)f2bf(v0.x); a[1] = (short)f2bf(v0.y);
        a[2] = (short)f2bf(v0.z); a[3] = (short)f2bf(v0.w);
        a[4] = (short)f2bf(v1.x); a[5] = (short)f2bf(v1.y);
        a[6] = (short)f2bf(v1.z); a[7] = (short)f2bf(v1.w);
#pragma unroll
        for (int t = 0; t < 4; t++)
            az[t] = __builtin_amdgcn_mfma_f32_16x16x32_bf16(a, bC[c][t], az[t], 0, 0, 0);
    }
    const float* dinv = ws + OFF_DINV;
    float dv[4];
#pragma unroll
    for (int r = 0; r < 4; r++) dv[r] = dinv[n0 + 4 * quad + r];
#pragma unroll
    for (int t = 0; t < 4; t++) {
        int ch = 16 * t + m;
#pragma unroll
        for (int r = 0; r < 4; r++)
            zbf[(size_t)(n0 + 4 * quad + r) * 64 + ch] = f2bf(az[t][r] * dv[r]);
    }
}

// ---------------- CSR build ----------------
__global__ void k_count(const int* __restrict__ col, int* __restrict__ cnt) {
    int t = blockIdx.x * 256 + threadIdx.x;
    if (t < E_MSG) atomicAdd(&cnt[col[t]], 1);
}

__global__ void __launch_bounds__(256) k_scan1(const int* __restrict__ cnt,
                                               int* __restrict__ bsum) {
    __shared__ int s[256];
    int n = blockIdx.x * 256 + threadIdx.x;
    s[threadIdx.x] = (n < N_NODES) ? cnt[n] : 0;
    __syncthreads();
    for (int off = 128; off > 0; off >>= 1) {
        if (threadIdx.x < off) s[threadIdx.x] += s[threadIdx.x + off];
        __syncthreads();
    }
    if (threadIdx.x == 0) bsum[blockIdx.x] = s[0];
}

__global__ void __launch_bounds__(256) k_scan2(int* __restrict__ bsum,
                                               int* __restrict__ ptr) {
    __shared__ int s[256];
    int t = threadIdx.x;
    int v = (t < SCAN_NB) ? bsum[t] : 0;
    s[t] = v;
    __syncthreads();
    for (int off = 1; off < 256; off <<= 1) {
        int u = (t >= off) ? s[t - off] : 0;
        __syncthreads();
        s[t] += u;
        __syncthreads();
    }
    if (t < SCAN_NB) bsum[t] = s[t] - v;
    if (t == 0) ptr[N_NODES] = E_MSG;
}

__global__ void __launch_bounds__(256) k_scan3(const int* __restrict__ cnt,
                                               const int* __restrict__ bsum,
                                               int* __restrict__ ptr,
                                               int* __restrict__ cur,
                                               float* __restrict__ dinv) {
    __shared__ int s[256];
    int t = threadIdx.x;
    int n = blockIdx.x * 256 + t;
    int v = (n < N_NODES) ? cnt[n] : 0;
    s[t] = v;
    __syncthreads();
    for (int off = 1; off < 256; off <<= 1) {
        int u = (t >= off) ? s[t - off] : 0;
        __syncthreads();
        s[t] += u;
        __syncthreads();
    }
    if (n < N_NODES) {
        int p = bsum[blockIdx.x] + s[t] - v;
        ptr[n] = p;
        cur[n] = p;
        dinv[n] = rsqrtf((float)v + 1.0f);
    }
}

__global__ void k_fill(const int* __restrict__ row, const int* __restrict__ col,
                       int* __restrict__ cur, int* __restrict__ elist) {
    int t = blockIdx.x * 256 + threadIdx.x;
    if (t < E_MSG) {
        int c = col[t];
        int pos = atomicAdd(&cur[c], 1);
        elist[pos] = row[t];
    }
}

// ---------------- fused gather + finalize ----------------
template <bool RELU, bool WRITE_OUT>
__global__ void __launch_bounds__(256) k_gather(const unsigned short* __restrict__ zbf,
                                                const int* __restrict__ ptr,
                                                const int* __restrict__ elist,
                                                const float* __restrict__ dinv,
                                                const float* __restrict__ bias,
                                                float* __restrict__ hout,
                                                unsigned short* __restrict__ hencbf,
                                                float* __restrict__ ofp) {
    int n = blockIdx.x * 4 + (threadIdx.x >> 6);
    int j = threadIdx.x & 63;
    int base = ptr[n];
    int end  = ptr[n + 1];
    float sum = bf2f(zbf[(size_t)n * 64 + j]);   // self-loop
    int k = base;
    for (; k + 16 <= end; k += 16) {
        int r[16];
#pragma unroll
        for (int q = 0; q < 16; q++) r[q] = elist[k + q];
        float v[16];
#pragma unroll
        for (int q = 0; q < 16; q++) v[q] = bf2f(zbf[(size_t)r[q] * 64 + j]);
        float s0 = ((v[0] + v[1]) + (v[2] + v[3])) + ((v[4] + v[5]) + (v[6] + v[7]));
        float s1 = ((v[8] + v[9]) + (v[10] + v[11])) + ((v[12] + v[13]) + (v[14] + v[15]));
        sum += s0 + s1;
    }
    for (; k + 4 <= end; k += 4) {
        int r0 = elist[k], r1 = elist[k + 1], r2 = elist[k + 2], r3 = elist[k + 3];
        float v0 = bf2f(zbf[(size_t)r0 * 64 + j]);
        float v1 = bf2f(zbf[(size_t)r1 * 64 + j]);
        float v2 = bf2f(zbf[(size_t)r2 * 64 + j]);
        float v3 = bf2f(zbf[(size_t)r3 * 64 + j]);
        sum += (v0 + v1) + (v2 + v3);
    }
    for (; k < end; k++)
        sum += bf2f(zbf[(size_t)elist[k] * 64 + j]);
    float v = dinv[n] * sum + bias[j];
    if (RELU) v = fmaxf(v, 0.0f);
    size_t t = (size_t)n * 64 + j;
    if (WRITE_OUT) {
        ofp[t] = v;
        hencbf[t] = f2bf(v);
    } else {
        hout[t] = v;
    }
}

// ---------------- edge decoder (MFMA bf16, pipelined) ----------------
#define DEC_TPW 4
#define DEC_TILES (E_FULL / 16)

__global__ void __launch_bounds__(256) k_dec(const int* __restrict__ src,
                                             const int* __restrict__ dst,
                                             const unsigned short* __restrict__ hbf,
                                             const float* __restrict__ ws,
                                             float* __restrict__ out) {
    int lane = threadIdx.x & 63;
    int wv = threadIdx.x >> 6;
    int m = lane & 15;
    int quad = lane >> 4;

    const unsigned short* fw = (const unsigned short*)(ws + OFF_FWD1);
    bf16x8 bfr[4][4];
#pragma unroll
    for (int c = 0; c < 4; c++)
#pragma unroll
        for (int t = 0; t < 4; t++)
            bfr[c][t] = *reinterpret_cast<const bf16x8*>(fw + (c * 4 + t) * 512 + lane * 8);

    float w2[4], b1v[4];
#pragma unroll
    for (int t = 0; t < 4; t++) {
        w2[t]  = ws[OFF_Wd2 + 16 * t + m];
        b1v[t] = ws[OFF_bd1 + 16 * t + m];
    }
    float b2 = ws[OFF_bd2];

    int tile0 = (blockIdx.x * 4 + wv) * DEC_TPW;
    int tc = min(tile0, DEC_TILES - 1);
    int s0 = src[tc * 16 + m], d0 = dst[tc * 16 + m];
    tc = min(tile0 + 1, DEC_TILES - 1);
    int s1 = src[tc * 16 + m], d1 = dst[tc * 16 + m];
    bf16x8 A0[4];
#pragma unroll
    for (int c = 0; c < 4; c++) {
        int row = (c < 2) ? s0 : d0;
        A0[c] = *reinterpret_cast<const bf16x8*>(
            hbf + (size_t)row * 64 + (c & 1) * 32 + 8 * quad);
    }

    for (int i = 0; i < DEC_TPW; i++) {
        int tile = tile0 + i;
        int t2 = min(tile0 + i + 2, DEC_TILES - 1);
        int s2 = src[t2 * 16 + m], d2 = dst[t2 * 16 + m];
        bf16x8 A1[4];
#pragma unroll
        for (int c = 0; c < 4; c++) {
            int row = (c < 2) ? s1 : d1;
            A1[c] = *reinterpret_cast<const bf16x8*>(
                hbf + (size_t)row * 64 + (c & 1) * 32 + 8 * quad);
        }
        f32x4 acc[4] = {f32x4{0,0,0,0}, f32x4{0,0,0,0}, f32x4{0,0,0,0}, f32x4{0,0,0,0}};
#pragma unroll
        for (int c = 0; c < 4; c++)
#pragma unroll
            for (int t = 0; t < 4; t++)
                acc[t] = __builtin_amdgcn_mfma_f32_16x16x32_bf16(A0[c], bfr[c][t], acc[t], 0, 0, 0);
        float sums[4];
#pragma unroll
        for (int r = 0; r < 4; r++) {
            float sv = 0.0f;
#pragma unroll
            for (int t = 0; t < 4; t++) {
                float v = acc[t][r] + b1v[t];
                float h = v * __builtin_amdgcn_rcpf(1.0f + __expf(-v));
                sv = fmaf(h, w2[t], sv);
            }
#pragma unroll
            for (int msk = 8; msk >= 1; msk >>= 1)
                sv += __shfl_xor(sv, msk, 64);
            sums[r] = sv;
        }
        if (m == 0 && tile < DEC_TILES) {
            int ebase = tile * 16 + 4 * quad;
#pragma unroll
            for (int r = 0; r < 4; r++) out[ebase + r] = sums[r] + b2;
        }
#pragma unroll
        for (int c = 0; c < 4; c++) A0[c] = A1[c];
        s1 = s2; d1 = d2;
    }
}

extern "C" void kernel_launch(void* const* d_in, const int* in_sizes, int n_in,
                              void* d_out, int out_size, void* d_ws, size_t ws_size,
                              hipStream_t stream) {
    if (n_in < 18) return;
    const void* x              = d_in[0];
    const int* edge_index      = (const int*)d_in[1];
    const int* full_edge_index = (const int*)d_in[2];
    const int* tsteps          = (const int*)d_in[3];
    float* ws = (float*)d_ws;
    float* out = (float*)d_out;

    int*   iws   = (int*)d_ws;
    int*   bsum  = iws + OFF_BSUM;
    int*   cnt   = iws + OFF_CNT;
    int*   ptr   = iws + OFF_PTR;
    int*   cur   = iws + OFF_CUR;
    int*   elist = iws + OFF_ELIST;
    unsigned short* zbf  = (unsigned short*)(ws + OFF_ZBF);
    unsigned short* henc = (unsigned short*)(ws + OFF_HENC);

    CvtArgs ca;
    for (int i = 0; i < 14; i++) ca.src[i] = d_in[4 + i];

    // CSR build (by dst) + dinv
    hipMemsetAsync(cnt, 0, (size_t)N_NODES * 4, stream);
    k_count<<<(E_MSG + 255) / 256, 256, 0, stream>>>(edge_index + E_MSG, cnt);
    k_scan1<<<SCAN_NB, 256, 0, stream>>>(cnt, bsum);
    k_scan2<<<1, 256, 0, stream>>>(bsum, ptr);
    k_scan3<<<SCAN_NB, 256, 0, stream>>>(cnt, bsum, ptr, cur, ws + OFF_DINV);
    k_fill<<<(E_MSG + 255) / 256, 256, 0, stream>>>(edge_index, edge_index + E_MSG,
                                                    cur, elist);

    // weights -> fp32, frag tables, t_emb table
    k_cvt<<<(W_TOTAL + 255) / 256, 256, 0, stream>>>(ca, ws);
    k_prep<<<96, 256, 0, stream>>>(ws);
    k_temb<<<T_STEPS, 64, 0, stream>>>(ws);

    // embedder + fused lin0 (h_embed -> d_out fp32; zbf0)
    k_embed<<<(N_NODES / 16 + 3) / 4, 256, 0, stream>>>(
        x, (const unsigned short*)d_in[4], tsteps, ws, out + E_FULL, zbf);

    // layer 0 gather -> h1 (A, relu)
    k_gather<true, false><<<N_NODES / 4, 256, 0, stream>>>(
        zbf, ptr, elist, ws + OFF_DINV, ws + OFF_bc0, ws + OFF_A, nullptr, nullptr);

    // lin1 (MFMA): A -> zbf1
    k_linm<<<(N_NODES / 16 + 3) / 4, 256, 0, stream>>>(ws + OFF_A, ws, zbf);

    // layer 1 gather -> {out fp32, henc bf16}
    k_gather<false, true><<<N_NODES / 4, 256, 0, stream>>>(
        zbf, ptr, elist, ws + OFF_DINV, ws + OFF_bc1, nullptr, henc,
        out + E_FULL + (size_t)N_NODES * 64);

    // decoder
    int dec_blocks = (DEC_TILES + 4 * DEC_TPW - 1) / (4 * DEC_TPW);
    k_dec<<<dec_blocks, 256, 0, stream>>>(full_edge_index, full_edge_index + E_FULL,
                                          henc, ws, out);
}

// Round 9
// 343.052 us; speedup vs baseline: 3.7899x; 1.0058x over previous
//
#include <hip/hip_runtime.h>
#include <hip/hip_bf16.h>
#include <math.h>

#define N_NODES 50000
#define E_MSG   800000
#define E_FULL  1000000
#define IN_C    128
#define H_C     64
#define T_STEPS 128

// ---- workspace layout (in floats) ----
#define OFF_Win   0
#define OFF_bin   8192
#define OFF_Wt1   8256
#define OFF_bt1   24640
#define OFF_Wt2   24896
#define OFF_bt2   41280
#define OFF_Wc0   41344
#define OFF_bc0   45440
#define OFF_Wc1   45504
#define OFF_bc1   49600
#define OFF_Wd1   49664
#define OFF_bd1   57856
#define OFF_Wd2   57920
#define OFF_bd2   57984
#define W_TOTAL   57985
#define OFF_BSUM  58016                 // 256 ints
#define OFF_FWD1  58368                 // 8192 fp8 bytes (16*Wd1 frag table, K=128)
#define OFF_FWIN  60416                 // 8192 bf16 (W_in frag table, K=128)
#define OFF_FWC0  64512                 // 4096 bf16 (Wc0 frag table, K=64)
#define OFF_TEMB  66560                 // 128*64 floats
#define OFF_DINV  74752                 // 50000 floats
#define OFF_CNT   124928                // 50000 ints
#define OFF_PTR   174928                // 50001 ints
#define OFF_CUR   224960                // 50000 ints
#define OFF_ELIST 275456                // 800000 ints
#define OFF_ZBF   1075456               // 3.2M bf16 (z0 table)
#define OFF_ZBF2  2675456               // 3.2M bf16 (z1 table)
#define OFF_HENC8 4275456               // 3.2M fp8 bytes (16*h_enc)
// total 5,075,456 floats = 20.3 MB

#define SCAN_NB   ((N_NODES + 255) / 256)   // 196

typedef __attribute__((ext_vector_type(8))) short bf16x8;
typedef __attribute__((ext_vector_type(4))) float f32x4;

static __device__ __forceinline__ float bf2f(unsigned short u) {
    return __uint_as_float(((unsigned)u) << 16);
}
static __device__ __forceinline__ unsigned short f2bf(float f) {
    unsigned u = __float_as_uint(f);
    unsigned r = (u + 0x7fffu + ((u >> 16) & 1u)) >> 16;
    return (unsigned short)r;
}
// fp32 -> fp8 e4m3fn, RNE, clamp to +-448
static __device__ __forceinline__ unsigned char f2fp8(float f) {
    unsigned u = __float_as_uint(f);
    unsigned s = (u >> 24) & 0x80;
    float a = fminf(__uint_as_float(u & 0x7FFFFFFF), 448.0f);
    if (a < 0.015625f) {                       // denormal result: quantum 2^-9
        int qi = (int)rintf(a * 512.0f);       // 0..8 (8 -> min normal)
        return (unsigned char)(s | qi);
    }
    unsigned ua = __float_as_uint(a);
    int e = (int)((ua >> 23) & 0xFF) - 127;    // -6..8
    unsigned man = (ua & 0x7FFFFF) | 0x800000; // 1.xx * 2^e, 24-bit
    unsigned r = man >> 20;                    // keep 4 bits (incl leading 1): 8..15
    unsigned rem = man & 0xFFFFF;
    if (rem > 0x80000u || (rem == 0x80000u && (r & 1))) r++;
    if (r == 16) { r = 8; e++; }
    if (e > 8) return (unsigned char)(s | 0x7E);
    return (unsigned char)(s | ((unsigned)(e + 7) << 3) | (r & 7));
}
// per-block input-dtype detection (bf16 vs fp32) from W_in's raw uint16s
static __device__ __forceinline__ bool detect_f32(const unsigned short* w, int* scnt) {
    if (threadIdx.x == 0) *scnt = 0;
    __syncthreads();
    int big = 0;
    for (int i = threadIdx.x; i < 2048; i += blockDim.x)
        if (fabsf(bf2f(w[2 * i])) > 0.5f) big++;
    atomicAdd(scnt, big);
    __syncthreads();
    return *scnt > 64;
}

// ---------------- weight conversion -> fp32, packed ----------------
struct CvtArgs { const void* src[14]; };

__global__ void k_cvt(CvtArgs a, float* ws) {
    __shared__ int scnt;
    bool f32 = detect_f32((const unsigned short*)a.src[0], &scnt);
    int t = blockIdx.x * 256 + threadIdx.x;
    if (t >= W_TOTAL) return;
    const int starts[14] = {OFF_Win, OFF_bin, OFF_Wt1, OFF_bt1, OFF_Wt2, OFF_bt2,
                            OFF_Wc0, OFF_bc0, OFF_Wc1, OFF_bc1, OFF_Wd1, OFF_bd1,
                            OFF_Wd2, OFF_bd2};
    int seg = 0;
#pragma unroll
    for (int i = 1; i < 14; i++)
        if (t >= starts[i]) seg = i;
    int off = t - starts[seg];
    ws[t] = f32 ? ((const float*)a.src[seg])[off]
                : bf2f(((const unsigned short*)a.src[seg])[off]);
}

// ---------------- MFMA B-fragment tables ----------------
// frag idx = (c*4+t)*512 + lane*8 + j -> W[(32c+8q+j)*64 + 16t+m]
__global__ void __launch_bounds__(256) k_prep(float* ws) {
    int idx = blockIdx.x * 256 + threadIdx.x;      // 0..20479
    int local, j, lane, ct, c, t, m, q;
    if (idx < 8192) {
        local = idx;
        j = local & 7; lane = (local >> 3) & 63; ct = local >> 9;
        c = ct >> 2; t = ct & 3; m = lane & 15; q = lane >> 4;
        ((unsigned char*)(ws + OFF_FWD1))[local] =
            f2fp8(16.0f * ws[OFF_Wd1 + (32 * c + 8 * q + j) * 64 + 16 * t + m]);
    } else if (idx < 16384) {
        local = idx - 8192;
        j = local & 7; lane = (local >> 3) & 63; ct = local >> 9;
        c = ct >> 2; t = ct & 3; m = lane & 15; q = lane >> 4;
        ((unsigned short*)(ws + OFF_FWIN))[local] =
            f2bf(ws[OFF_Win + (32 * c + 8 * q + j) * 64 + 16 * t + m]);
    } else if (idx < 20480) {
        local = idx - 16384;
        j = local & 7; lane = (local >> 3) & 63; ct = local >> 9;
        c = ct >> 2; t = ct & 3; m = lane & 15; q = lane >> 4;
        ((unsigned short*)(ws + OFF_FWC0))[local] =
            f2bf(ws[OFF_Wc0 + (32 * c + 8 * q + j) * 64 + 16 * t + m]);
    }
}

// ---------------- t_emb table ----------------
__global__ void __launch_bounds__(64) k_temb(float* ws) {
    const float* Wt1 = ws + OFF_Wt1;
    const float* bt1 = ws + OFF_bt1;
    const float* Wt2 = ws + OFF_Wt2;
    const float* bt2 = ws + OFF_bt2;
    float* temb = ws + OFF_TEMB;
    int t = blockIdx.x;
    int j = threadIdx.x;

    __shared__ float pe[64];
    __shared__ float us[256];

    float xt = (float)t * (4000.0f / 128.0f);
    float sc = -logf(10000.0f) / 31.0f;
    int idx = j & 31;
    float fr = __expf((float)idx * sc);
    float ang = xt * fr;
    pe[j] = (j < 32) ? sinf(ang) : cosf(ang);
    __syncthreads();

    float u[4];
#pragma unroll
    for (int q = 0; q < 4; q++) u[q] = bt1[q * 64 + j];
    for (int k = 0; k < 64; k++) {
        float p = pe[k];
#pragma unroll
        for (int q = 0; q < 4; q++)
            u[q] = fmaf(p, Wt1[k * 256 + q * 64 + j], u[q]);
    }
#pragma unroll
    for (int q = 0; q < 4; q++) {
        float uu = u[q];
        us[q * 64 + j] = uu * __builtin_amdgcn_rcpf(1.0f + __expf(-uu));
    }
    __syncthreads();

    float acc = bt2[j];
    for (int k = 0; k < 256; k++)
        acc = fmaf(us[k], Wt2[k * 64 + j], acc);
    temb[t * 64 + j] = acc;
}

// ---------------- embedder + fused GCN-linear-0 (MFMA x2) ----------------
__global__ void __launch_bounds__(256) k_embed(const void* __restrict__ xraw,
                                               const unsigned short* __restrict__ wdet,
                                               const int* __restrict__ tsteps,
                                               float* __restrict__ ws,
                                               float* __restrict__ out_hembed,
                                               unsigned short* __restrict__ zbf) {
    __shared__ int scnt;
    __shared__ unsigned short tl[4][16 * 64];
    bool f32 = detect_f32(wdet, &scnt);

    int lane = threadIdx.x & 63;
    int wv = threadIdx.x >> 6;
    int m = lane & 15, quad = lane >> 4;
    int wid = blockIdx.x * 4 + wv;
    if (wid > N_NODES / 16 - 1) wid = N_NODES / 16 - 1;   // clamp (dup work benign)
    int n0 = wid * 16;

    const unsigned short* fwin = (const unsigned short*)(ws + OFF_FWIN);
    const unsigned short* fwc0 = (const unsigned short*)(ws + OFF_FWC0);

    bf16x8 bI[4][4];
#pragma unroll
    for (int c = 0; c < 4; c++)
#pragma unroll
        for (int t = 0; t < 4; t++)
            bI[c][t] = *reinterpret_cast<const bf16x8*>(fwin + (c * 4 + t) * 512 + lane * 8);

    f32x4 acc[4] = {f32x4{0,0,0,0}, f32x4{0,0,0,0}, f32x4{0,0,0,0}, f32x4{0,0,0,0}};
#pragma unroll
    for (int c = 0; c < 4; c++) {
        bf16x8 a;
        if (f32) {
            const float* xp = (const float*)xraw + (size_t)(n0 + m) * 128 + 32 * c + 8 * quad;
            float4 v0 = *reinterpret_cast<const float4*>(xp);
            float4 v1 = *reinterpret_cast<const float4*>(xp + 4);
            a[0] = (short)f2bf(v0.x); a[1] = (short)f2bf(v0.y);
            a[2] = (short)f2bf(v0.z); a[3] = (short)f2bf(v0.w);
            a[4] = (short)f2bf(v1.x); a[5] = (short)f2bf(v1.y);
            a[6] = (short)f2bf(v1.z); a[7] = (short)f2bf(v1.w);
        } else {
            a = *reinterpret_cast<const bf16x8*>(
                (const unsigned short*)xraw + (size_t)(n0 + m) * 128 + 32 * c + 8 * quad);
        }
#pragma unroll
        for (int t = 0; t < 4; t++)
            acc[t] = __builtin_amdgcn_mfma_f32_16x16x32_bf16(a, bI[c][t], acc[t], 0, 0, 0);
    }

    int tn[4];
#pragma unroll
    for (int r = 0; r < 4; r++) tn[r] = tsteps[n0 + 4 * quad + r];
    const float* temb = ws + OFF_TEMB;
#pragma unroll
    for (int t = 0; t < 4; t++) {
        int ch = 16 * t + m;
        float bj = ws[OFF_bin + ch];
#pragma unroll
        for (int r = 0; r < 4; r++) {
            int node = n0 + 4 * quad + r;
            float v = acc[t][r] + bj + temb[tn[r] * 64 + ch];
            out_hembed[(size_t)node * 64 + ch] = v;
            tl[wv][(4 * quad + r) * 64 + ch] = f2bf(v);
        }
    }
    __syncthreads();   // all waves active (wid clamped) -> safe

    // stage 2: lin0 via MFMA on the LDS tile
    bf16x8 bC[2][4];
#pragma unroll
    for (int c = 0; c < 2; c++)
#pragma unroll
        for (int t = 0; t < 4; t++)
            bC[c][t] = *reinterpret_cast<const bf16x8*>(fwc0 + (c * 4 + t) * 512 + lane * 8);

    f32x4 az[4] = {f32x4{0,0,0,0}, f32x4{0,0,0,0}, f32x4{0,0,0,0}, f32x4{0,0,0,0}};
#pragma unroll
    for (int c = 0; c < 2; c++) {
        bf16x8 a2 = *reinterpret_cast<const bf16x8*>(&tl[wv][m * 64 + 32 * c + 8 * quad]);
#pragma unroll
        for (int t = 0; t < 4; t++)
            az[t] = __builtin_amdgcn_mfma_f32_16x16x32_bf16(a2, bC[c][t], az[t], 0, 0, 0);
    }
    const float* dinv = ws + OFF_DINV;
    float dv[4];
#pragma unroll
    for (int r = 0; r < 4; r++) dv[r] = dinv[n0 + 4 * quad + r];
#pragma unroll
    for (int t = 0; t < 4; t++) {
        int ch = 16 * t + m;
#pragma unroll
        for (int r = 0; r < 4; r++)
            zbf[(size_t)(n0 + 4 * quad + r) * 64 + ch] = f2bf(az[t][r] * dv[r]);
    }
}

// ---------------- CSR build ----------------
__global__ void k_count(const int* __restrict__ col, int* __restrict__ cnt) {
    int t = blockIdx.x * 256 + threadIdx.x;
    if (t < E_MSG) atomicAdd(&cnt[col[t]], 1);
}

__global__ void __launch_bounds__(256) k_scan1(const int* __restrict__ cnt,
                                               int* __restrict__ bsum) {
    __shared__ int s[256];
    int n = blockIdx.x * 256 + threadIdx.x;
    s[threadIdx.x] = (n < N_NODES) ? cnt[n] : 0;
    __syncthreads();
    for (int off = 128; off > 0; off >>= 1) {
        if (threadIdx.x < off) s[threadIdx.x] += s[threadIdx.x + off];
        __syncthreads();
    }
    if (threadIdx.x == 0) bsum[blockIdx.x] = s[0];
}

__global__ void __launch_bounds__(256) k_scan2(int* __restrict__ bsum,
                                               int* __restrict__ ptr) {
    __shared__ int s[256];
    int t = threadIdx.x;
    int v = (t < SCAN_NB) ? bsum[t] : 0;
    s[t] = v;
    __syncthreads();
    for (int off = 1; off < 256; off <<= 1) {
        int u = (t >= off) ? s[t - off] : 0;
        __syncthreads();
        s[t] += u;
        __syncthreads();
    }
    if (t < SCAN_NB) bsum[t] = s[t] - v;
    if (t == 0) ptr[N_NODES] = E_MSG;
}

__global__ void __launch_bounds__(256) k_scan3(const int* __restrict__ cnt,
                                               const int* __restrict__ bsum,
                                               int* __restrict__ ptr,
                                               int* __restrict__ cur,
                                               float* __restrict__ dinv) {
    __shared__ int s[256];
    int t = threadIdx.x;
    int n = blockIdx.x * 256 + t;
    int v = (n < N_NODES) ? cnt[n] : 0;
    s[t] = v;
    __syncthreads();
    for (int off = 1; off < 256; off <<= 1) {
        int u = (t >= off) ? s[t - off] : 0;
        __syncthreads();
        s[t] += u;
        __syncthreads();
    }
    if (n < N_NODES) {
        int p = bsum[blockIdx.x] + s[t] - v;
        ptr[n] = p;
        cur[n] = p;
        dinv[n] = rsqrtf((float)v + 1.0f);
    }
}

__global__ void k_fill(const int* __restrict__ row, const int* __restrict__ col,
                       int* __restrict__ cur, int* __restrict__ elist) {
    int t = blockIdx.x * 256 + threadIdx.x;
    if (t < E_MSG) {
        int c = col[t];
        int pos = atomicAdd(&cur[c], 1);
        elist[pos] = row[t];
    }
}

// ---------------- gather-0 + relu + fused GCN-linear-1 ----------------
// wave = node. h1 stays in LDS; z1 = (h1 @ Wc1)*dinv computed fp32, -> zbf2.
__global__ void __launch_bounds__(256) k_gather0(const unsigned short* __restrict__ zbf,
                                                 const int* __restrict__ ptr,
                                                 const int* __restrict__ elist,
                                                 const float* __restrict__ dinv,
                                                 const float* __restrict__ bias,
                                                 const float* __restrict__ Wc1,
                                                 unsigned short* __restrict__ zout) {
    __shared__ float hsh[4][64];
    int wv = threadIdx.x >> 6;
    int j = threadIdx.x & 63;
    int n = blockIdx.x * 4 + wv;
    int base = ptr[n];
    int end  = ptr[n + 1];
    float sum = bf2f(zbf[(size_t)n * 64 + j]);   // self-loop
    int k = base;
    for (; k + 16 <= end; k += 16) {
        int r[16];
#pragma unroll
        for (int q = 0; q < 16; q++) r[q] = elist[k + q];
        float v[16];
#pragma unroll
        for (int q = 0; q < 16; q++) v[q] = bf2f(zbf[(size_t)r[q] * 64 + j]);
        float s0 = ((v[0] + v[1]) + (v[2] + v[3])) + ((v[4] + v[5]) + (v[6] + v[7]));
        float s1 = ((v[8] + v[9]) + (v[10] + v[11])) + ((v[12] + v[13]) + (v[14] + v[15]));
        sum += s0 + s1;
    }
    for (; k + 4 <= end; k += 4) {
        int r0 = elist[k], r1 = elist[k + 1], r2 = elist[k + 2], r3 = elist[k + 3];
        float v0 = bf2f(zbf[(size_t)r0 * 64 + j]);
        float v1 = bf2f(zbf[(size_t)r1 * 64 + j]);
        float v2 = bf2f(zbf[(size_t)r2 * 64 + j]);
        float v3 = bf2f(zbf[(size_t)r3 * 64 + j]);
        sum += (v0 + v1) + (v2 + v3);
    }
    for (; k < end; k++)
        sum += bf2f(zbf[(size_t)elist[k] * 64 + j]);
    float h = fmaxf(dinv[n] * sum + bias[j], 0.0f);
    hsh[wv][j] = h;
    __syncthreads();

    float z = 0.0f;
#pragma unroll 16
    for (int kk = 0; kk < 64; kk++)
        z = fmaf(hsh[wv][kk], Wc1[kk * 64 + j], z);
    zout[(size_t)n * 64 + j] = f2bf(z * dinv[n]);
}

// ---------------- gather-1 -> h_enc (fp32 out + fp8x16 table) ----------------
__global__ void __launch_bounds__(256) k_gather1(const unsigned short* __restrict__ zbf,
                                                 const int* __restrict__ ptr,
                                                 const int* __restrict__ elist,
                                                 const float* __restrict__ dinv,
                                                 const float* __restrict__ bias,
                                                 unsigned char* __restrict__ henc8,
                                                 float* __restrict__ ofp) {
    int n = blockIdx.x * 4 + (threadIdx.x >> 6);
    int j = threadIdx.x & 63;
    int base = ptr[n];
    int end  = ptr[n + 1];
    float sum = bf2f(zbf[(size_t)n * 64 + j]);   // self-loop
    int k = base;
    for (; k + 16 <= end; k += 16) {
        int r[16];
#pragma unroll
        for (int q = 0; q < 16; q++) r[q] = elist[k + q];
        float v[16];
#pragma unroll
        for (int q = 0; q < 16; q++) v[q] = bf2f(zbf[(size_t)r[q] * 64 + j]);
        float s0 = ((v[0] + v[1]) + (v[2] + v[3])) + ((v[4] + v[5]) + (v[6] + v[7]));
        float s1 = ((v[8] + v[9]) + (v[10] + v[11])) + ((v[12] + v[13]) + (v[14] + v[15]));
        sum += s0 + s1;
    }
    for (; k + 4 <= end; k += 4) {
        int r0 = elist[k], r1 = elist[k + 1], r2 = elist[k + 2], r3 = elist[k + 3];
        float v0 = bf2f(zbf[(size_t)r0 * 64 + j]);
        float v1 = bf2f(zbf[(size_t)r1 * 64 + j]);
        float v2 = bf2f(zbf[(size_t)r2 * 64 + j]);
        float v3 = bf2f(zbf[(size_t)r3 * 64 + j]);
        sum += (v0 + v1) + (v2 + v3);
    }
    for (; k < end; k++)
        sum += bf2f(zbf[(size_t)elist[k] * 64 + j]);
    float v = dinv[n] * sum + bias[j];
    size_t t = (size_t)n * 64 + j;
    ofp[t] = v;
    henc8[t] = f2fp8(16.0f * v);
}

// ---------------- edge decoder (MFMA fp8, pipelined) ----------------
#define DEC_TPW 4
#define DEC_TILES (E_FULL / 16)

__global__ void __launch_bounds__(256) k_dec(const int* __restrict__ src,
                                             const int* __restrict__ dst,
                                             const unsigned char* __restrict__ h8,
                                             const float* __restrict__ ws,
                                             float* __restrict__ out) {
    int lane = threadIdx.x & 63;
    int wv = threadIdx.x >> 6;
    int m = lane & 15;
    int quad = lane >> 4;

    const unsigned char* fw = (const unsigned char*)(ws + OFF_FWD1);
    long bfr[4][4];
#pragma unroll
    for (int c = 0; c < 4; c++)
#pragma unroll
        for (int t = 0; t < 4; t++)
            bfr[c][t] = *reinterpret_cast<const long*>(fw + ((c * 4 + t) * 512 + lane * 8));

    float w2[4], b1v[4];
#pragma unroll
    for (int t = 0; t < 4; t++) {
        w2[t]  = ws[OFF_Wd2 + 16 * t + m];
        b1v[t] = ws[OFF_bd1 + 16 * t + m];
    }
    float b2 = ws[OFF_bd2];

    int tile0 = (blockIdx.x * 4 + wv) * DEC_TPW;
    int tc = min(tile0, DEC_TILES - 1);
    int s0 = src[tc * 16 + m], d0 = dst[tc * 16 + m];
    tc = min(tile0 + 1, DEC_TILES - 1);
    int s1 = src[tc * 16 + m], d1 = dst[tc * 16 + m];
    long A0[4];
#pragma unroll
    for (int c = 0; c < 4; c++) {
        int row = (c < 2) ? s0 : d0;
        A0[c] = *reinterpret_cast<const long*>(
            h8 + (size_t)row * 64 + (c & 1) * 32 + 8 * quad);
    }

    for (int i = 0; i < DEC_TPW; i++) {
        int tile = tile0 + i;
        int t2 = min(tile0 + i + 2, DEC_TILES - 1);
        int s2 = src[t2 * 16 + m], d2 = dst[t2 * 16 + m];
        long A1[4];
#pragma unroll
        for (int c = 0; c < 4; c++) {
            int row = (c < 2) ? s1 : d1;
            A1[c] = *reinterpret_cast<const long*>(
                h8 + (size_t)row * 64 + (c & 1) * 32 + 8 * quad);
        }
        f32x4 acc[4] = {f32x4{0,0,0,0}, f32x4{0,0,0,0}, f32x4{0,0,0,0}, f32x4{0,0,0,0}};
#pragma unroll
        for (int c = 0; c < 4; c++)
#pragma unroll
            for (int t = 0; t < 4; t++)
                acc[t] = __builtin_amdgcn_mfma_f32_16x16x32_fp8_fp8(A0[c], bfr[c][t], acc[t], 0, 0, 0);
        float sums[4];
#pragma unroll
        for (int r = 0; r < 4; r++) {
            float sv = 0.0f;
#pragma unroll
            for (int t = 0; t < 4; t++) {
                float v = fmaf(acc[t][r], 0.00390625f, b1v[t]);   // /256 un-scale
                float h = v * __builtin_amdgcn_rcpf(1.0f + __expf(-v));
                sv = fmaf(h, w2[t], sv);
            }
#pragma unroll
            for (int msk = 8; msk >= 1; msk >>= 1)
                sv += __shfl_xor(sv, msk, 64);
            sums[r] = sv;
        }
        if (m == 0 && tile < DEC_TILES) {
            int ebase = tile * 16 + 4 * quad;
#pragma unroll
            for (int r = 0; r < 4; r++) out[ebase + r] = sums[r] + b2;
        }
#pragma unroll
        for (int c = 0; c < 4; c++) A0[c] = A1[c];
        s1 = s2; d1 = d2;
    }
}

extern "C" void kernel_launch(void* const* d_in, const int* in_sizes, int n_in,
                              void* d_out, int out_size, void* d_ws, size_t ws_size,
                              hipStream_t stream) {
    if (n_in < 18) return;
    const void* x              = d_in[0];
    const int* edge_index      = (const int*)d_in[1];
    const int* full_edge_index = (const int*)d_in[2];
    const int* tsteps          = (const int*)d_in[3];
    float* ws = (float*)d_ws;
    float* out = (float*)d_out;

    int*   iws   = (int*)d_ws;
    int*   bsum  = iws + OFF_BSUM;
    int*   cnt   = iws + OFF_CNT;
    int*   ptr   = iws + OFF_PTR;
    int*   cur   = iws + OFF_CUR;
    int*   elist = iws + OFF_ELIST;
    unsigned short* zbf  = (unsigned short*)(ws + OFF_ZBF);
    unsigned short* zbf2 = (unsigned short*)(ws + OFF_ZBF2);
    unsigned char*  h8   = (unsigned char*)(ws + OFF_HENC8);

    CvtArgs ca;
    for (int i = 0; i < 14; i++) ca.src[i] = d_in[4 + i];

    // CSR build (by dst) + dinv
    hipMemsetAsync(cnt, 0, (size_t)N_NODES * 4, stream);
    k_count<<<(E_MSG + 255) / 256, 256, 0, stream>>>(edge_index + E_MSG, cnt);
    k_scan1<<<SCAN_NB, 256, 0, stream>>>(cnt, bsum);
    k_scan2<<<1, 256, 0, stream>>>(bsum, ptr);
    k_scan3<<<SCAN_NB, 256, 0, stream>>>(cnt, bsum, ptr, cur, ws + OFF_DINV);
    k_fill<<<(E_MSG + 255) / 256, 256, 0, stream>>>(edge_index, edge_index + E_MSG,
                                                    cur, elist);

    // weights -> fp32, frag tables, t_emb table
    k_cvt<<<(W_TOTAL + 255) / 256, 256, 0, stream>>>(ca, ws);
    k_prep<<<80, 256, 0, stream>>>(ws);
    k_temb<<<T_STEPS, 64, 0, stream>>>(ws);

    // embedder + fused lin0 (h_embed -> d_out fp32; z0 -> zbf)
    k_embed<<<(N_NODES / 16 + 3) / 4, 256, 0, stream>>>(
        x, (const unsigned short*)d_in[4], tsteps, ws, out + E_FULL, zbf);

    // gather0 + relu + fused lin1: zbf -> zbf2
    k_gather0<<<N_NODES / 4, 256, 0, stream>>>(
        zbf, ptr, elist, ws + OFF_DINV, ws + OFF_bc0, ws + OFF_Wc1, zbf2);

    // gather1: zbf2 -> {out fp32, h8 fp8x16}
    k_gather1<<<N_NODES / 4, 256, 0, stream>>>(
        zbf2, ptr, elist, ws + OFF_DINV, ws + OFF_bc1, h8,
        out + E_FULL + (size_t)N_NODES * 64);

    // decoder (fp8 MFMA)
    int dec_blocks = (DEC_TILES + 4 * DEC_TPW - 1) / (4 * DEC_TPW);
    k_dec<<<dec_blocks, 256, 0, stream>>>(full_edge_index, full_edge_index + E_FULL,
                                          h8, ws, out);
}